// Round 2
// baseline (1621.704 us; speedup 1.0000x reference)
//
#include <hip/hip_runtime.h>
#include <math.h>

#define DM 128            // d_model
#define HEADS 4
#define DH 32             // d_head

// ---------------- embed: h = X + Seed*Wseed + D*Wdeg + C*Wclu ---------------
// one thread = 4 dims (float4)
__global__ void embed_kernel(const float* __restrict__ X, const float* __restrict__ Seed,
                             const float* __restrict__ Dg, const float* __restrict__ Cl,
                             const float* __restrict__ Wseed, const float* __restrict__ Wdeg,
                             const float* __restrict__ Wclu, float* __restrict__ H, int n) {
    int i = blockIdx.x * blockDim.x + threadIdx.x;
    if (i >= n * (DM / 4)) return;
    int nd = i >> 5, d4 = (i & 31) * 4;
    float x = X[nd], sd = Seed[nd], dg = Dg[nd], cl = Cl[nd];
    float4 ws = *reinterpret_cast<const float4*>(Wseed + d4);
    float4 wd = *reinterpret_cast<const float4*>(Wdeg + d4);
    float4 wc = *reinterpret_cast<const float4*>(Wclu + d4);
    float4 o;
    o.x = x + sd * ws.x + dg * wd.x + cl * wc.x;
    o.y = x + sd * ws.y + dg * wd.y + cl * wc.y;
    o.z = x + sd * ws.z + dg * wd.z + cl * wc.z;
    o.w = x + sd * ws.w + dg * wd.w + cl * wc.w;
    *reinterpret_cast<float4*>(H + nd * DM + d4) = o;
}

// ---------------- CSR build -------------------------------------------------
__global__ void count_kernel(const int* __restrict__ edst, int* __restrict__ deg, int E) {
    int e = blockIdx.x * blockDim.x + threadIdx.x;
    if (e < E) atomicAdd(&deg[edst[e]], 1);
}

__global__ void scan1_kernel(const int* __restrict__ in, int* __restrict__ outv,
                             int* __restrict__ bsums, int n) {
    __shared__ int s[256];
    int t = threadIdx.x;
    int i = blockIdx.x * 256 + t;
    int v = (i < n) ? in[i] : 0;
    s[t] = v;
    __syncthreads();
    for (int off = 1; off < 256; off <<= 1) {
        int x = (t >= off) ? s[t - off] : 0;
        __syncthreads();
        s[t] += x;
        __syncthreads();
    }
    if (i < n) outv[i] = s[t];
    if (t == 255) bsums[blockIdx.x] = s[255];
}

__global__ void scan2_kernel(int* __restrict__ bsums, int nb) {
    __shared__ int s[256];
    int t = threadIdx.x;
    int v = (t < nb) ? bsums[t] : 0;
    s[t] = v;
    __syncthreads();
    for (int off = 1; off < 256; off <<= 1) {
        int x = (t >= off) ? s[t - off] : 0;
        __syncthreads();
        s[t] += x;
        __syncthreads();
    }
    if (t < nb) bsums[t] = s[t];
}

__global__ void scan3_kernel(const int* __restrict__ outv, const int* __restrict__ bsums,
                             int* __restrict__ ptr, int n) {
    int i = blockIdx.x * 256 + threadIdx.x;
    if (i == 0) ptr[0] = 0;
    if (i < n) {
        int add = (blockIdx.x > 0) ? bsums[blockIdx.x - 1] : 0;
        ptr[i + 1] = outv[i] + add;
    }
}

__global__ void scatter_kernel(const int* __restrict__ esrc, const int* __restrict__ edst,
                               const int* __restrict__ ptr, int* __restrict__ fill,
                               int* __restrict__ out, int E) {
    int e = blockIdx.x * blockDim.x + threadIdx.x;
    if (e >= E) return;
    int d = edst[e];
    int pos = ptr[d] + atomicAdd(&fill[d], 1);
    out[pos] = esrc[e];
}

// ---------------- cache-resident GEMM: O[n x 128] = A[n x 128] @ W ----------
// 256 threads, tile 64 rows x 128 cols, per-thread 4x8. No LDS, no barriers;
// A tile (32KB) L1-resident, W (64KB) L2-resident. ldO lets K/V pack into one
// [N][256] buffer.
__global__ __launch_bounds__(256) void gemm_cache_kernel(const float* __restrict__ A,
                                                         const float* __restrict__ W,
                                                         float* __restrict__ O, int ldO,
                                                         int n) {
    int t = threadIdx.x;
    int rg = t >> 4, cg = t & 15;
    int row0 = blockIdx.x * 64 + rg * 4;
    const float* a0 = A + (size_t)min(row0 + 0, n - 1) * DM;
    const float* a1 = A + (size_t)min(row0 + 1, n - 1) * DM;
    const float* a2 = A + (size_t)min(row0 + 2, n - 1) * DM;
    const float* a3 = A + (size_t)min(row0 + 3, n - 1) * DM;
    const float* wp = W + cg * 8;

    float acc[4][8];
#pragma unroll
    for (int i = 0; i < 4; i++)
#pragma unroll
        for (int j = 0; j < 8; j++) acc[i][j] = 0.f;

#pragma unroll 2
    for (int k4 = 0; k4 < DM / 4; k4++) {
        float av0[4], av1[4], av2[4], av3[4];
        *reinterpret_cast<float4*>(av0) = *reinterpret_cast<const float4*>(a0 + k4 * 4);
        *reinterpret_cast<float4*>(av1) = *reinterpret_cast<const float4*>(a1 + k4 * 4);
        *reinterpret_cast<float4*>(av2) = *reinterpret_cast<const float4*>(a2 + k4 * 4);
        *reinterpret_cast<float4*>(av3) = *reinterpret_cast<const float4*>(a3 + k4 * 4);
#pragma unroll
        for (int kk = 0; kk < 4; kk++) {
            float wv[8];
            *reinterpret_cast<float4*>(wv) =
                *reinterpret_cast<const float4*>(wp + (k4 * 4 + kk) * DM);
            *reinterpret_cast<float4*>(wv + 4) =
                *reinterpret_cast<const float4*>(wp + (k4 * 4 + kk) * DM + 4);
#pragma unroll
            for (int j = 0; j < 8; j++) {
                acc[0][j] += av0[kk] * wv[j];
                acc[1][j] += av1[kk] * wv[j];
                acc[2][j] += av2[kk] * wv[j];
                acc[3][j] += av3[kk] * wv[j];
            }
        }
    }
#pragma unroll
    for (int i = 0; i < 4; i++) {
        int gr = row0 + i;
        if (gr < n) {
            *reinterpret_cast<float4*>(O + (size_t)gr * ldO + cg * 8) =
                make_float4(acc[i][0], acc[i][1], acc[i][2], acc[i][3]);
            *reinterpret_cast<float4*>(O + (size_t)gr * ldO + cg * 8 + 4) =
                make_float4(acc[i][4], acc[i][5], acc[i][6], acc[i][7]);
        }
    }
}

// ---------------- attention: one wave per dst node --------------------------
// lane l holds dims (2l, 2l+1); head = l>>4 occupies 16 contiguous lanes.
// KV packed [N][256]: k row at +0, v row at +128. exp2-based online softmax.
__global__ __launch_bounds__(256) void attn_kernel(const float* __restrict__ Q,
                                                   const float* __restrict__ KV,
                                                   const int* __restrict__ ptr,
                                                   const int* __restrict__ esrc,
                                                   float* __restrict__ AGG, int n) {
    int w = threadIdx.x >> 6;
    int lane = threadIdx.x & 63;
    int node = blockIdx.x * 4 + w;
    if (node >= n) return;
    // 1/sqrt(32) * log2(e): softmax in base 2 == base e exactly
    const float scale = 0.17677669529663687f * 1.4426950408889634f;
    float2 q = *reinterpret_cast<const float2*>(Q + node * DM + 2 * lane);
    q.x *= scale; q.y *= scale;
    float m = -INFINITY, s = 0.f;
    float accx = 0.f, accy = 0.f;
    int e0 = ptr[node], e1 = ptr[node + 1];
    for (int e = e0; e < e1; e++) {
        int src = esrc[e];
        const float* kp = KV + (size_t)src * 256 + 2 * lane;
        float2 k2 = *reinterpret_cast<const float2*>(kp);
        float2 v2 = *reinterpret_cast<const float2*>(kp + 128);
        float p = q.x * k2.x + q.y * k2.y;
        p += __shfl_xor(p, 1, 64);
        p += __shfl_xor(p, 2, 64);
        p += __shfl_xor(p, 4, 64);
        p += __shfl_xor(p, 8, 64);
        float mn = fmaxf(m, p);
        float d = exp2f(m - mn);
        float wg = exp2f(p - mn);
        s = s * d + wg;
        accx = accx * d + wg * v2.x;
        accy = accy * d + wg * v2.y;
        m = mn;
    }
    float inv = 1.f / (s + 1e-9f);
    *reinterpret_cast<float2*>(AGG + node * DM + 2 * lane) = make_float2(accx * inv, accy * inv);
}

// ---------------- MLP head as GEMM + fused epilogue -------------------------
// out[row] = relu(H[row]@W1 + b1) @ W2 + b2 ; same tiling as gemm_cache.
__global__ __launch_bounds__(256) void mlp_kernel(const float* __restrict__ H,
                                                  const float* __restrict__ W1,
                                                  const float* __restrict__ b1,
                                                  const float* __restrict__ W2,
                                                  const float* __restrict__ b2,
                                                  float* __restrict__ out, int n) {
    int t = threadIdx.x;
    int rg = t >> 4, cg = t & 15;
    int row0 = blockIdx.x * 64 + rg * 4;
    const float* a0 = H + (size_t)min(row0 + 0, n - 1) * DM;
    const float* a1 = H + (size_t)min(row0 + 1, n - 1) * DM;
    const float* a2 = H + (size_t)min(row0 + 2, n - 1) * DM;
    const float* a3 = H + (size_t)min(row0 + 3, n - 1) * DM;
    const float* wp = W1 + cg * 8;

    float acc[4][8];
#pragma unroll
    for (int i = 0; i < 4; i++)
#pragma unroll
        for (int j = 0; j < 8; j++) acc[i][j] = 0.f;

#pragma unroll 2
    for (int k4 = 0; k4 < DM / 4; k4++) {
        float av0[4], av1[4], av2[4], av3[4];
        *reinterpret_cast<float4*>(av0) = *reinterpret_cast<const float4*>(a0 + k4 * 4);
        *reinterpret_cast<float4*>(av1) = *reinterpret_cast<const float4*>(a1 + k4 * 4);
        *reinterpret_cast<float4*>(av2) = *reinterpret_cast<const float4*>(a2 + k4 * 4);
        *reinterpret_cast<float4*>(av3) = *reinterpret_cast<const float4*>(a3 + k4 * 4);
#pragma unroll
        for (int kk = 0; kk < 4; kk++) {
            float wv[8];
            *reinterpret_cast<float4*>(wv) =
                *reinterpret_cast<const float4*>(wp + (k4 * 4 + kk) * DM);
            *reinterpret_cast<float4*>(wv + 4) =
                *reinterpret_cast<const float4*>(wp + (k4 * 4 + kk) * DM + 4);
#pragma unroll
            for (int j = 0; j < 8; j++) {
                acc[0][j] += av0[kk] * wv[j];
                acc[1][j] += av1[kk] * wv[j];
                acc[2][j] += av2[kk] * wv[j];
                acc[3][j] += av3[kk] * wv[j];
            }
        }
    }
    // epilogue: relu(acc + b1) dot W2, reduce across the 16 col-threads
    float b1v[8], w2v[8];
#pragma unroll
    for (int j = 0; j < 8; j++) {
        b1v[j] = b1[cg * 8 + j];
        w2v[j] = W2[cg * 8 + j];
    }
    float b2v = b2[0];
#pragma unroll
    for (int i = 0; i < 4; i++) {
        float part = 0.f;
#pragma unroll
        for (int j = 0; j < 8; j++) {
            float z = fmaxf(acc[i][j] + b1v[j], 0.f);
            part += z * w2v[j];
        }
        part += __shfl_xor(part, 1, 64);
        part += __shfl_xor(part, 2, 64);
        part += __shfl_xor(part, 4, 64);
        part += __shfl_xor(part, 8, 64);
        int gr = row0 + i;
        if (cg == 0 && gr < n) out[gr] = part + b2v;
    }
}

// ---------------------------------------------------------------------------
extern "C" void kernel_launch(void* const* d_in, const int* in_sizes, int n_in,
                              void* d_out, int out_size, void* d_ws, size_t ws_size,
                              hipStream_t stream) {
    const float* X    = (const float*)d_in[0];
    const float* Seed = (const float*)d_in[1];
    const float* Dg   = (const float*)d_in[2];
    const float* Cl   = (const float*)d_in[3];
    const int* esrc   = (const int*)d_in[4];
    const int* edst   = (const int*)d_in[5];
    const float* Wseed = (const float*)d_in[6];
    const float* Wdeg  = (const float*)d_in[7];
    const float* Wclu  = (const float*)d_in[8];
    const float* Wq = (const float*)d_in[9];
    const float* Wk = (const float*)d_in[10];
    const float* Wv = (const float*)d_in[11];
    const float* Wo = (const float*)d_in[12];
    const float* W1 = (const float*)d_in[13];
    const float* b1 = (const float*)d_in[14];
    const float* W2 = (const float*)d_in[15];
    const float* b2 = (const float*)d_in[16];
    float* out = (float*)d_out;

    int n = in_sizes[0];
    int E = in_sizes[4];

    char* p = (char*)d_ws;
    auto alloc = [&](size_t bytes) {
        void* r = (void*)p;
        p += (bytes + 255) & ~(size_t)255;
        return r;
    };
    float* hbuf = (float*)alloc((size_t)n * DM * 4);      // h
    float* qbuf = (float*)alloc((size_t)n * DM * 4);      // q
    float* kvbuf = (float*)alloc((size_t)n * 256 * 4);    // packed K|V
    float* abuf = (float*)alloc((size_t)n * DM * 4);      // agg
    int* deg    = (int*)alloc((size_t)n * 4);
    int* ptr    = (int*)alloc((size_t)(n + 1) * 4);
    int* ptrtmp = (int*)alloc((size_t)n * 4);
    int* bsums  = (int*)alloc(1024);
    int* fill   = (int*)alloc((size_t)n * 4);
    int* esrcs  = (int*)alloc((size_t)E * 4);
    (void)ws_size; (void)n_in; (void)out_size;

    hipMemsetAsync(deg, 0, (size_t)n * 4, stream);
    hipMemsetAsync(fill, 0, (size_t)n * 4, stream);

    {
        int total = n * (DM / 4);
        embed_kernel<<<(total + 255) / 256, 256, 0, stream>>>(X, Seed, Dg, Cl, Wseed, Wdeg,
                                                              Wclu, hbuf, n);
    }
    int nb = (n + 255) / 256;
    count_kernel<<<(E + 255) / 256, 256, 0, stream>>>(edst, deg, E);
    scan1_kernel<<<nb, 256, 0, stream>>>(deg, ptrtmp, bsums, n);
    scan2_kernel<<<1, 256, 0, stream>>>(bsums, nb);
    scan3_kernel<<<nb, 256, 0, stream>>>(ptrtmp, bsums, ptr, n);
    scatter_kernel<<<(E + 255) / 256, 256, 0, stream>>>(esrc, edst, ptr, fill, esrcs, E);

    int ggrid = (n + 63) / 64;
    int agrid = (n + 3) / 4;
    for (int i = 0; i < 3; i++) {
        const float* wq = Wq + (size_t)i * DM * DM;
        const float* wk = Wk + (size_t)i * DM * DM;
        const float* wv = Wv + (size_t)i * DM * DM;
        const float* wo = Wo + (size_t)i * DM * DM;
        gemm_cache_kernel<<<ggrid, 256, 0, stream>>>(hbuf, wq, qbuf, DM, n);
        gemm_cache_kernel<<<ggrid, 256, 0, stream>>>(hbuf, wk, kvbuf, 256, n);
        gemm_cache_kernel<<<ggrid, 256, 0, stream>>>(hbuf, wv, kvbuf + 128, 256, n);
        attn_kernel<<<agrid, 256, 0, stream>>>(qbuf, kvbuf, ptr, esrcs, abuf, n);
        gemm_cache_kernel<<<ggrid, 256, 0, stream>>>(abuf, wo, hbuf, DM, n);
    }
    mlp_kernel<<<ggrid, 256, 0, stream>>>(hbuf, W1, b1, W2, b2, out, n);
}

// Round 4
// 1281.690 us; speedup vs baseline: 1.2653x; 1.2653x over previous
//
#include <hip/hip_runtime.h>
#include <math.h>

#define DM 128            // d_model
#define HEADS 4
#define DH 32             // d_head

// ---------------- helpers ---------------------------------------------------
__device__ __forceinline__ uint32_t pk_bf16(float lo, float hi) {
    // round-to-nearest-even bf16 pair packed in one u32 (lo in low half)
    uint32_t a = __builtin_bit_cast(uint32_t, lo);
    uint32_t b = __builtin_bit_cast(uint32_t, hi);
    a = (a + 0x7fffu + ((a >> 16) & 1u)) >> 16;
    b = (b + 0x7fffu + ((b >> 16) & 1u)) & 0xffff0000u;
    return b | a;
}

// ---------------- embed: h = X + Seed*Wseed + D*Wdeg + C*Wclu ---------------
__global__ void embed_kernel(const float* __restrict__ X, const float* __restrict__ Seed,
                             const float* __restrict__ Dg, const float* __restrict__ Cl,
                             const float* __restrict__ Wseed, const float* __restrict__ Wdeg,
                             const float* __restrict__ Wclu, float* __restrict__ H, int n) {
    int i = blockIdx.x * blockDim.x + threadIdx.x;
    if (i >= n * (DM / 4)) return;
    int nd = i >> 5, d4 = (i & 31) * 4;
    float x = X[nd], sd = Seed[nd], dg = Dg[nd], cl = Cl[nd];
    float4 ws = *reinterpret_cast<const float4*>(Wseed + d4);
    float4 wd = *reinterpret_cast<const float4*>(Wdeg + d4);
    float4 wc = *reinterpret_cast<const float4*>(Wclu + d4);
    float4 o;
    o.x = x + sd * ws.x + dg * wd.x + cl * wc.x;
    o.y = x + sd * ws.y + dg * wd.y + cl * wc.y;
    o.z = x + sd * ws.z + dg * wd.z + cl * wc.z;
    o.w = x + sd * ws.w + dg * wd.w + cl * wc.w;
    *reinterpret_cast<float4*>(H + nd * DM + d4) = o;
}

// ---------------- CSR build -------------------------------------------------
__global__ void count_kernel(const int* __restrict__ edst, int* __restrict__ deg, int E) {
    int e = blockIdx.x * blockDim.x + threadIdx.x;
    if (e < E) atomicAdd(&deg[edst[e]], 1);
}

__global__ void scan1_kernel(const int* __restrict__ in, int* __restrict__ outv,
                             int* __restrict__ bsums, int n) {
    __shared__ int s[256];
    int t = threadIdx.x;
    int i = blockIdx.x * 256 + t;
    int v = (i < n) ? in[i] : 0;
    s[t] = v;
    __syncthreads();
    for (int off = 1; off < 256; off <<= 1) {
        int x = (t >= off) ? s[t - off] : 0;
        __syncthreads();
        s[t] += x;
        __syncthreads();
    }
    if (i < n) outv[i] = s[t];
    if (t == 255) bsums[blockIdx.x] = s[255];
}

__global__ void scan2_kernel(int* __restrict__ bsums, int nb) {
    __shared__ int s[256];
    int t = threadIdx.x;
    int v = (t < nb) ? bsums[t] : 0;
    s[t] = v;
    __syncthreads();
    for (int off = 1; off < 256; off <<= 1) {
        int x = (t >= off) ? s[t - off] : 0;
        __syncthreads();
        s[t] += x;
        __syncthreads();
    }
    if (t < nb) bsums[t] = s[t];
}

__global__ void scan3_kernel(const int* __restrict__ outv, const int* __restrict__ bsums,
                             int* __restrict__ ptr, int n) {
    int i = blockIdx.x * 256 + threadIdx.x;
    if (i == 0) ptr[0] = 0;
    if (i < n) {
        int add = (blockIdx.x > 0) ? bsums[blockIdx.x - 1] : 0;
        ptr[i + 1] = outv[i] + add;
    }
}

__global__ void scatter_kernel(const int* __restrict__ esrc, const int* __restrict__ edst,
                               const int* __restrict__ ptr, int* __restrict__ fill,
                               int* __restrict__ out, int E) {
    int e = blockIdx.x * blockDim.x + threadIdx.x;
    if (e >= E) return;
    int d = edst[e];
    int pos = ptr[d] + atomicAdd(&fill[d], 1);
    out[pos] = esrc[e];
}

// ---------------- GEMM v3: O[n x 128] = A[n x 128] @ W[128 x 128] -----------
// 256 threads, tile 64 rows x 128 cols, per-thread 4x8.
// A staged in LDS (64 x 132 pad, 33.8KB -> 4 blocks/CU), read as ds_read_b128.
// W streamed from global (L2-resident, 256B/wave-instr).
// BF16OUT packs RNE bf16 pairs (for the attention KV buffer).
template <bool BF16OUT>
__global__ __launch_bounds__(256) void gemm_kernel(const float* __restrict__ A,
                                                   const float* __restrict__ W,
                                                   void* __restrict__ O, int ldO, int n) {
    __shared__ float sA[64 * 132];
    int t = threadIdx.x;
    int row0 = blockIdx.x * 64;

    // stage A tile: 2048 float4, 8 per thread
#pragma unroll
    for (int p = 0; p < 8; p++) {
        int f = p * 256 + t;
        int r = f >> 5, c4 = (f & 31) * 4;
        int gr = min(row0 + r, n - 1);
        float4 val = *reinterpret_cast<const float4*>(A + (size_t)gr * DM + c4);
        *reinterpret_cast<float4*>(&sA[r * 132 + c4]) = val;
    }
    __syncthreads();

    int rg = t >> 4, cg = t & 15;
    const float* pa = &sA[rg * 4 * 132];
    const float* wp = W + cg * 8;

    float acc[4][8];
#pragma unroll
    for (int i = 0; i < 4; i++)
#pragma unroll
        for (int j = 0; j < 8; j++) acc[i][j] = 0.f;

#pragma unroll 2
    for (int k4 = 0; k4 < DM / 4; k4++) {
        float av0[4], av1[4], av2[4], av3[4];
        *reinterpret_cast<float4*>(av0) = *reinterpret_cast<const float4*>(pa + 0 * 132 + k4 * 4);
        *reinterpret_cast<float4*>(av1) = *reinterpret_cast<const float4*>(pa + 1 * 132 + k4 * 4);
        *reinterpret_cast<float4*>(av2) = *reinterpret_cast<const float4*>(pa + 2 * 132 + k4 * 4);
        *reinterpret_cast<float4*>(av3) = *reinterpret_cast<const float4*>(pa + 3 * 132 + k4 * 4);
#pragma unroll
        for (int kk = 0; kk < 4; kk++) {
            float wv[8];
            *reinterpret_cast<float4*>(wv) =
                *reinterpret_cast<const float4*>(wp + (k4 * 4 + kk) * DM);
            *reinterpret_cast<float4*>(wv + 4) =
                *reinterpret_cast<const float4*>(wp + (k4 * 4 + kk) * DM + 4);
#pragma unroll
            for (int j = 0; j < 8; j++) {
                acc[0][j] += av0[kk] * wv[j];
                acc[1][j] += av1[kk] * wv[j];
                acc[2][j] += av2[kk] * wv[j];
                acc[3][j] += av3[kk] * wv[j];
            }
        }
    }

#pragma unroll
    for (int i = 0; i < 4; i++) {
        int gr = row0 + rg * 4 + i;
        if (gr >= n) continue;
        if (BF16OUT) {
            unsigned short* ob = (unsigned short*)O;
            uint4 pk;
            pk.x = pk_bf16(acc[i][0], acc[i][1]);
            pk.y = pk_bf16(acc[i][2], acc[i][3]);
            pk.z = pk_bf16(acc[i][4], acc[i][5]);
            pk.w = pk_bf16(acc[i][6], acc[i][7]);
            *reinterpret_cast<uint4*>(ob + (size_t)gr * ldO + cg * 8) = pk;
        } else {
            float* of = (float*)O;
            *reinterpret_cast<float4*>(of + (size_t)gr * ldO + cg * 8) =
                make_float4(acc[i][0], acc[i][1], acc[i][2], acc[i][3]);
            *reinterpret_cast<float4*>(of + (size_t)gr * ldO + cg * 8 + 4) =
                make_float4(acc[i][4], acc[i][5], acc[i][6], acc[i][7]);
        }
    }
}

// ---------------- attention: one wave per dst node, bf16 KV gather ----------
// lane l holds dims (2l, 2l+1); head = l>>4 in 16 contiguous lanes.
// KV row = 128 u32 (256 bf16): K pair at [lane], V pair at [64+lane].
__global__ __launch_bounds__(256) void attn_kernel(const float* __restrict__ Q,
                                                   const uint32_t* __restrict__ KV,
                                                   const int* __restrict__ ptr,
                                                   const int* __restrict__ esrc,
                                                   float* __restrict__ AGG, int n) {
    int w = threadIdx.x >> 6;
    int lane = threadIdx.x & 63;
    int node = blockIdx.x * 4 + w;
    if (node >= n) return;
    // 1/sqrt(32) * log2(e): exp2-based softmax == exp-based exactly
    const float scale = 0.17677669529663687f * 1.4426950408889634f;
    float2 q = *reinterpret_cast<const float2*>(Q + (size_t)node * DM + 2 * lane);
    float qx = q.x * scale, qy = q.y * scale;
    float m = -INFINITY, s = 0.f, ax = 0.f, ay = 0.f;
    int e0 = ptr[node], e1 = ptr[node + 1];
    uint32_t ku = 0, vu = 0;
    if (e0 < e1) {
        const uint32_t* r = KV + (size_t)esrc[e0] * 128;
        ku = r[lane];
        vu = r[64 + lane];
    }
    for (int e = e0; e < e1; e++) {
        uint32_t kc = ku, vc = vu;
        if (e + 1 < e1) {
            const uint32_t* r = KV + (size_t)esrc[e + 1] * 128;
            ku = r[lane];
            vu = r[64 + lane];
        }
        float kx = __builtin_bit_cast(float, kc << 16);
        float ky = __builtin_bit_cast(float, kc & 0xffff0000u);
        float p = qx * kx + qy * ky;
        p += __shfl_xor(p, 1, 64);
        p += __shfl_xor(p, 2, 64);
        p += __shfl_xor(p, 4, 64);
        p += __shfl_xor(p, 8, 64);
        float mn = fmaxf(m, p);
        float d = exp2f(m - mn);
        float wg = exp2f(p - mn);
        float vx = __builtin_bit_cast(float, vc << 16);
        float vy = __builtin_bit_cast(float, vc & 0xffff0000u);
        s = s * d + wg;
        ax = ax * d + wg * vx;
        ay = ay * d + wg * vy;
        m = mn;
    }
    float inv = 1.f / (s + 1e-9f);
    *reinterpret_cast<float2*>(AGG + (size_t)node * DM + 2 * lane) =
        make_float2(ax * inv, ay * inv);
}

// ---------------- MLP head: relu(H@W1+b1)@W2 + b2, LDS-A GEMM + epilogue ----
__global__ __launch_bounds__(256) void mlp_kernel(const float* __restrict__ H,
                                                  const float* __restrict__ W1,
                                                  const float* __restrict__ b1,
                                                  const float* __restrict__ W2,
                                                  const float* __restrict__ b2,
                                                  float* __restrict__ out, int n) {
    __shared__ float sA[64 * 132];
    int t = threadIdx.x;
    int row0 = blockIdx.x * 64;
#pragma unroll
    for (int p = 0; p < 8; p++) {
        int f = p * 256 + t;
        int r = f >> 5, c4 = (f & 31) * 4;
        int gr = min(row0 + r, n - 1);
        float4 val = *reinterpret_cast<const float4*>(H + (size_t)gr * DM + c4);
        *reinterpret_cast<float4*>(&sA[r * 132 + c4]) = val;
    }
    __syncthreads();

    int rg = t >> 4, cg = t & 15;
    const float* pa = &sA[rg * 4 * 132];
    const float* wp = W1 + cg * 8;

    float acc[4][8];
#pragma unroll
    for (int i = 0; i < 4; i++)
#pragma unroll
        for (int j = 0; j < 8; j++) acc[i][j] = 0.f;

#pragma unroll 2
    for (int k4 = 0; k4 < DM / 4; k4++) {
        float av0[4], av1[4], av2[4], av3[4];
        *reinterpret_cast<float4*>(av0) = *reinterpret_cast<const float4*>(pa + 0 * 132 + k4 * 4);
        *reinterpret_cast<float4*>(av1) = *reinterpret_cast<const float4*>(pa + 1 * 132 + k4 * 4);
        *reinterpret_cast<float4*>(av2) = *reinterpret_cast<const float4*>(pa + 2 * 132 + k4 * 4);
        *reinterpret_cast<float4*>(av3) = *reinterpret_cast<const float4*>(pa + 3 * 132 + k4 * 4);
#pragma unroll
        for (int kk = 0; kk < 4; kk++) {
            float wv[8];
            *reinterpret_cast<float4*>(wv) =
                *reinterpret_cast<const float4*>(wp + (k4 * 4 + kk) * DM);
            *reinterpret_cast<float4*>(wv + 4) =
                *reinterpret_cast<const float4*>(wp + (k4 * 4 + kk) * DM + 4);
#pragma unroll
            for (int j = 0; j < 8; j++) {
                acc[0][j] += av0[kk] * wv[j];
                acc[1][j] += av1[kk] * wv[j];
                acc[2][j] += av2[kk] * wv[j];
                acc[3][j] += av3[kk] * wv[j];
            }
        }
    }

    float b1v[8], w2v[8];
#pragma unroll
    for (int j = 0; j < 8; j++) {
        b1v[j] = b1[cg * 8 + j];
        w2v[j] = W2[cg * 8 + j];
    }
    float b2v = b2[0];
#pragma unroll
    for (int i = 0; i < 4; i++) {
        float part = 0.f;
#pragma unroll
        for (int j = 0; j < 8; j++) {
            float z = fmaxf(acc[i][j] + b1v[j], 0.f);
            part += z * w2v[j];
        }
        part += __shfl_xor(part, 1, 64);
        part += __shfl_xor(part, 2, 64);
        part += __shfl_xor(part, 4, 64);
        part += __shfl_xor(part, 8, 64);
        int gr = row0 + rg * 4 + i;
        if (cg == 0 && gr < n) out[gr] = part + b2v;
    }
}

// ---------------------------------------------------------------------------
extern "C" void kernel_launch(void* const* d_in, const int* in_sizes, int n_in,
                              void* d_out, int out_size, void* d_ws, size_t ws_size,
                              hipStream_t stream) {
    const float* X    = (const float*)d_in[0];
    const float* Seed = (const float*)d_in[1];
    const float* Dg   = (const float*)d_in[2];
    const float* Cl   = (const float*)d_in[3];
    const int* esrc   = (const int*)d_in[4];
    const int* edst   = (const int*)d_in[5];
    const float* Wseed = (const float*)d_in[6];
    const float* Wdeg  = (const float*)d_in[7];
    const float* Wclu  = (const float*)d_in[8];
    const float* Wq = (const float*)d_in[9];
    const float* Wk = (const float*)d_in[10];
    const float* Wv = (const float*)d_in[11];
    const float* Wo = (const float*)d_in[12];
    const float* W1 = (const float*)d_in[13];
    const float* b1 = (const float*)d_in[14];
    const float* W2 = (const float*)d_in[15];
    const float* b2 = (const float*)d_in[16];
    float* out = (float*)d_out;

    int n = in_sizes[0];
    int E = in_sizes[4];

    char* p = (char*)d_ws;
    auto alloc = [&](size_t bytes) {
        void* r = (void*)p;
        p += (bytes + 255) & ~(size_t)255;
        return r;
    };
    float* hbuf  = (float*)alloc((size_t)n * DM * 4);         // h
    float* qbuf  = (float*)alloc((size_t)n * DM * 4);         // q
    float* abuf  = (float*)alloc((size_t)n * DM * 4);         // agg
    unsigned short* kvbuf = (unsigned short*)alloc((size_t)n * 256 * 2);  // bf16 K|V
    int* deg    = (int*)alloc((size_t)n * 4);
    int* ptr    = (int*)alloc((size_t)(n + 1) * 4);
    int* ptrtmp = (int*)alloc((size_t)n * 4);
    int* bsums  = (int*)alloc(1024);
    int* fill   = (int*)alloc((size_t)n * 4);
    int* esrcs  = (int*)alloc((size_t)E * 4);
    (void)ws_size; (void)n_in; (void)out_size;

    hipMemsetAsync(deg, 0, (size_t)n * 4, stream);
    hipMemsetAsync(fill, 0, (size_t)n * 4, stream);

    {
        int total = n * (DM / 4);
        embed_kernel<<<(total + 255) / 256, 256, 0, stream>>>(X, Seed, Dg, Cl, Wseed, Wdeg,
                                                              Wclu, hbuf, n);
    }
    int nb = (n + 255) / 256;
    count_kernel<<<(E + 255) / 256, 256, 0, stream>>>(edst, deg, E);
    scan1_kernel<<<nb, 256, 0, stream>>>(deg, ptrtmp, bsums, n);
    scan2_kernel<<<1, 256, 0, stream>>>(bsums, nb);
    scan3_kernel<<<nb, 256, 0, stream>>>(ptrtmp, bsums, ptr, n);
    scatter_kernel<<<(E + 255) / 256, 256, 0, stream>>>(esrc, edst, ptr, fill, esrcs, E);

    int ggrid = (n + 63) / 64;
    int agrid = (n + 3) / 4;
    for (int i = 0; i < 3; i++) {
        const float* wq = Wq + (size_t)i * DM * DM;
        const float* wk = Wk + (size_t)i * DM * DM;
        const float* wv = Wv + (size_t)i * DM * DM;
        const float* wo = Wo + (size_t)i * DM * DM;
        gemm_kernel<false><<<ggrid, 256, 0, stream>>>(hbuf, wq, qbuf, DM, n);
        gemm_kernel<true><<<ggrid, 256, 0, stream>>>(hbuf, wk, kvbuf, 256, n);
        gemm_kernel<true><<<ggrid, 256, 0, stream>>>(hbuf, wv, kvbuf + 128, 256, n);
        attn_kernel<<<agrid, 256, 0, stream>>>(qbuf, (const uint32_t*)kvbuf, ptr, esrcs,
                                               abuf, n);
        gemm_kernel<false><<<ggrid, 256, 0, stream>>>(abuf, wo, hbuf, DM, n);
    }
    mlp_kernel<<<ggrid, 256, 0, stream>>>(hbuf, W1, b1, W2, b2, out, n);
}

// Round 6
// 814.967 us; speedup vs baseline: 1.9899x; 1.5727x over previous
//
#include <hip/hip_runtime.h>
#include <math.h>

#define DM 128            // d_model
#define HEADS 4
#define DH 32             // d_head
#define WSTRIDE 16384     // 128x128 fp16 elements per packed weight matrix

typedef _Float16 f16x8 __attribute__((ext_vector_type(8)));
typedef _Float16 f16x4 __attribute__((ext_vector_type(4)));
typedef _Float16 f16x2 __attribute__((ext_vector_type(2)));
typedef float f32x4v __attribute__((ext_vector_type(4)));

// ---------------- embed: h = X + Seed*Wseed + D*Wdeg + C*Wclu ---------------
__global__ void embed_kernel(const float* __restrict__ X, const float* __restrict__ Seed,
                             const float* __restrict__ Dg, const float* __restrict__ Cl,
                             const float* __restrict__ Wseed, const float* __restrict__ Wdeg,
                             const float* __restrict__ Wclu, float* __restrict__ H, int n) {
    int i = blockIdx.x * blockDim.x + threadIdx.x;
    if (i >= n * (DM / 4)) return;
    int nd = i >> 5, d4 = (i & 31) * 4;
    float x = X[nd], sd = Seed[nd], dg = Dg[nd], cl = Cl[nd];
    float4 ws = *reinterpret_cast<const float4*>(Wseed + d4);
    float4 wd = *reinterpret_cast<const float4*>(Wdeg + d4);
    float4 wc = *reinterpret_cast<const float4*>(Wclu + d4);
    float4 o;
    o.x = x + sd * ws.x + dg * wd.x + cl * wc.x;
    o.y = x + sd * ws.y + dg * wd.y + cl * wc.y;
    o.z = x + sd * ws.z + dg * wd.z + cl * wc.z;
    o.w = x + sd * ws.w + dg * wd.w + cl * wc.w;
    *reinterpret_cast<float4*>(H + nd * DM + d4) = o;
}

// ---------------- CSR build -------------------------------------------------
__global__ void count_kernel(const int* __restrict__ edst, int* __restrict__ deg, int E) {
    int e = blockIdx.x * blockDim.x + threadIdx.x;
    if (e < E) atomicAdd(&deg[edst[e]], 1);
}

__global__ void scan1_kernel(const int* __restrict__ in, int* __restrict__ outv,
                             int* __restrict__ bsums, int n) {
    __shared__ int s[256];
    int t = threadIdx.x;
    int i = blockIdx.x * 256 + t;
    int v = (i < n) ? in[i] : 0;
    s[t] = v;
    __syncthreads();
    for (int off = 1; off < 256; off <<= 1) {
        int x = (t >= off) ? s[t - off] : 0;
        __syncthreads();
        s[t] += x;
        __syncthreads();
    }
    if (i < n) outv[i] = s[t];
    if (t == 255) bsums[blockIdx.x] = s[255];
}

__global__ void scan2_kernel(int* __restrict__ bsums, int nb) {
    __shared__ int s[256];
    int t = threadIdx.x;
    int v = (t < nb) ? bsums[t] : 0;
    s[t] = v;
    __syncthreads();
    for (int off = 1; off < 256; off <<= 1) {
        int x = (t >= off) ? s[t - off] : 0;
        __syncthreads();
        s[t] += x;
        __syncthreads();
    }
    if (t < nb) bsums[t] = s[t];
}

__global__ void scan3_kernel(const int* __restrict__ outv, const int* __restrict__ bsums,
                             int* __restrict__ ptr, int n) {
    int i = blockIdx.x * 256 + threadIdx.x;
    if (i == 0) ptr[0] = 0;
    if (i < n) {
        int add = (blockIdx.x > 0) ? bsums[blockIdx.x - 1] : 0;
        ptr[i + 1] = outv[i] + add;
    }
}

__global__ void scatter_kernel(const int* __restrict__ esrc, const int* __restrict__ edst,
                               const int* __restrict__ ptr, int* __restrict__ fill,
                               int* __restrict__ out, int E) {
    int e = blockIdx.x * blockDim.x + threadIdx.x;
    if (e >= E) return;
    int d = edst[e];
    int pos = ptr[d] + atomicAdd(&fill[d], 1);
    out[pos] = esrc[e];
}

// ---------------- W prepack: fp32 [128x128] -> fp16 MFMA-fragment order -----
// frag index: ((kb*8+nb)*64 + lane)*8 + j  <=>  W[kb*32+(lane>>4)*8+j][nb*16+(lane&15)]
// 32 (kb,nb) blocks * 64 lanes * 8 = 16384 elements per matrix (WSTRIDE).
// matrices: 0..2 Wq, 3..5 Wk, 6..8 Wv, 9..11 Wo, 12 W1
__global__ void prepack_kernel(const float* __restrict__ Wq, const float* __restrict__ Wk,
                               const float* __restrict__ Wv, const float* __restrict__ Wo,
                               const float* __restrict__ W1, _Float16* __restrict__ W16) {
    int m = blockIdx.z;
    const float* W;
    if (m < 3)       W = Wq + (size_t)m * DM * DM;
    else if (m < 6)  W = Wk + (size_t)(m - 3) * DM * DM;
    else if (m < 9)  W = Wv + (size_t)(m - 6) * DM * DM;
    else if (m < 12) W = Wo + (size_t)(m - 9) * DM * DM;
    else             W = W1;
    int kb = blockIdx.x, nb = blockIdx.y, l = threadIdx.x;
    int kbase = kb * 32 + (l >> 4) * 8;
    int c = nb * 16 + (l & 15);
    f16x8 v;
#pragma unroll
    for (int j = 0; j < 8; j++) v[j] = (_Float16)W[(kbase + j) * DM + c];
    *reinterpret_cast<f16x8*>(W16 + (size_t)m * WSTRIDE + ((kb * 8 + nb) * 64 + l) * 8) = v;
}

// ---------------- MFMA GEMM: O[n x 128] = A[n x 128] @ W -------------------
// 256 thr = 4 waves; wave w: rows [blk*64 + w*16, +16), all 128 cols.
// A fp32 -> fp16 LDS [64][136] (16B-aligned rows).
// OUT: 0 = fp32 store (ldO, colOff=0), 1 = fp16 store into KV (ldO=256, colOff).
template <int OUT>
__global__ __launch_bounds__(256) void gemm_mfma_kernel(const float* __restrict__ A,
                                                        const _Float16* __restrict__ W16,
                                                        void* __restrict__ O, int ldO,
                                                        int colOff, int n) {
    __shared__ _Float16 sA[64 * 136];
    int t = threadIdx.x;
    int row0 = blockIdx.x * 64;
#pragma unroll
    for (int p = 0; p < 8; p++) {
        int f = p * 256 + t;
        int r = f >> 5, c4 = (f & 31) * 4;
        int gr = min(row0 + r, n - 1);
        float4 v = *reinterpret_cast<const float4*>(A + (size_t)gr * DM + c4);
        f16x4 h = {(_Float16)v.x, (_Float16)v.y, (_Float16)v.z, (_Float16)v.w};
        *reinterpret_cast<f16x4*>(&sA[r * 136 + c4]) = h;
    }
    __syncthreads();

    int w = t >> 6, l = t & 63;
    int lr = l & 15, lg = l >> 4;
    int rowb = w * 16;

    f32x4v acc[8];
#pragma unroll
    for (int nb = 0; nb < 8; nb++) acc[nb] = (f32x4v){0.f, 0.f, 0.f, 0.f};

#pragma unroll
    for (int kb = 0; kb < 4; kb++) {
        f16x8 a = *reinterpret_cast<const f16x8*>(&sA[(rowb + lr) * 136 + kb * 32 + lg * 8]);
#pragma unroll
        for (int nb = 0; nb < 8; nb++) {
            f16x8 b = *reinterpret_cast<const f16x8*>(&W16[((kb * 8 + nb) * 64 + l) * 8]);
            acc[nb] = __builtin_amdgcn_mfma_f32_16x16x32_f16(a, b, acc[nb], 0, 0, 0);
        }
    }

#pragma unroll
    for (int nb = 0; nb < 8; nb++) {
#pragma unroll
        for (int i = 0; i < 4; i++) {
            int r = row0 + rowb + lg * 4 + i;
            if (r >= n) continue;
            int c = nb * 16 + lr;
            if (OUT == 0) {
                ((float*)O)[(size_t)r * ldO + c] = acc[nb][i];
            } else {
                _Float16 h = (_Float16)acc[nb][i];
                ((unsigned short*)O)[(size_t)r * ldO + colOff + c] =
                    __builtin_bit_cast(unsigned short, h);
            }
        }
    }
}

// ---------------- attention: one wave per dst node, fp16 KV, 2 chains -------
// lane l = dims (2l,2l+1); head = l>>4 (16 lanes). KV row: 128 u32 = 256 f16.
__global__ __launch_bounds__(256) void attn_kernel(const float* __restrict__ Q,
                                                   const uint32_t* __restrict__ KV,
                                                   const int* __restrict__ ptr,
                                                   const int* __restrict__ esrc,
                                                   float* __restrict__ AGG, int n) {
    int w = threadIdx.x >> 6;
    int lane = threadIdx.x & 63;
    int node = blockIdx.x * 4 + w;
    if (node >= n) return;
    int e0 = ptr[node], e1 = ptr[node + 1];
    float2* outp = reinterpret_cast<float2*>(AGG + (size_t)node * DM + 2 * lane);
    if (e0 >= e1) {
        *outp = make_float2(0.f, 0.f);
        return;
    }
    // scale applied post-reduce; includes log2(e) for exp2-softmax (== exp exactly)
    const float scale = 0.17677669529663687f * 1.4426950408889634f;
    float2 qf = *reinterpret_cast<const float2*>(Q + (size_t)node * DM + 2 * lane);
    f16x2 qh = {(_Float16)qf.x, (_Float16)qf.y};

    float mA = -INFINITY, sA = 0.f, axA = 0.f, ayA = 0.f;
    float mB = -INFINITY, sB = 0.f, axB = 0.f, ayB = 0.f;

    int cnt = e1 - e0;
    int npairs = cnt >> 1;
    int last = e1 - 1;

    auto kvrow = [&](int src) { return KV + (size_t)src * 128; };

    // pipeline: data for pairs p, p+1 in regs; indices for pair p+2 in regs
    int iA2 = 0, iB2 = 0;
    uint32_t kA0 = 0, vA0 = 0, kB0 = 0, vB0 = 0;
    uint32_t kA1 = 0, vA1 = 0, kB1 = 0, vB1 = 0;
    {
        int b0 = e0;
        int iA0 = esrc[min(b0, last)];
        int iB0 = esrc[min(b0 + 1, last)];
        const uint32_t* rA = kvrow(iA0);
        const uint32_t* rB = kvrow(iB0);
        kA0 = rA[lane]; vA0 = rA[64 + lane];
        kB0 = rB[lane]; vB0 = rB[64 + lane];
        int b1 = e0 + 2;
        int iA1 = esrc[min(b1, last)];
        int iB1 = esrc[min(b1 + 1, last)];
        const uint32_t* rA1 = kvrow(iA1);
        const uint32_t* rB1 = kvrow(iB1);
        kA1 = rA1[lane]; vA1 = rA1[64 + lane];
        kB1 = rB1[lane]; vB1 = rB1[64 + lane];
        int b2 = e0 + 4;
        iA2 = esrc[min(b2, last)];
        iB2 = esrc[min(b2 + 1, last)];
    }

#define PROC(kc, vc, m_, s_, ax_, ay_)                                         \
    {                                                                          \
        float p = __builtin_amdgcn_fdot2(qh, __builtin_bit_cast(f16x2, kc),    \
                                         0.f, false);                          \
        p += __shfl_xor(p, 1, 64);                                             \
        p += __shfl_xor(p, 2, 64);                                             \
        p += __shfl_xor(p, 4, 64);                                             \
        p += __shfl_xor(p, 8, 64);                                             \
        p *= scale;                                                            \
        float mn = fmaxf(m_, p);                                               \
        float dd = exp2f(m_ - mn);                                             \
        float wg = exp2f(p - mn);                                              \
        f16x2 vh = __builtin_bit_cast(f16x2, vc);                              \
        s_ = s_ * dd + wg;                                                     \
        ax_ = ax_ * dd + wg * (float)vh[0];                                    \
        ay_ = ay_ * dd + wg * (float)vh[1];                                    \
        m_ = mn;                                                               \
    }

    for (int p = 0; p < npairs; p++) {
        uint32_t kAc = kA0, vAc = vA0, kBc = kB0, vBc = vB0;
        // shift pipeline
        kA0 = kA1; vA0 = vA1; kB0 = kB1; vB0 = vB1;
        // issue loads for pair p+2 (indices already in regs)
        const uint32_t* rA = kvrow(iA2);
        const uint32_t* rB = kvrow(iB2);
        kA1 = rA[lane]; vA1 = rA[64 + lane];
        kB1 = rB[lane]; vB1 = rB[64 + lane];
        // fetch indices for pair p+3
        int b = e0 + 2 * (p + 3);
        iA2 = esrc[min(b, last)];
        iB2 = esrc[min(b + 1, last)];
        // process current pair (two independent chains)
        PROC(kAc, vAc, mA, sA, axA, ayA);
        PROC(kBc, vBc, mB, sB, axB, ayB);
    }
    if (cnt & 1) {
        const uint32_t* r = kvrow(esrc[last]);
        uint32_t kc = r[lane], vc = r[64 + lane];
        PROC(kc, vc, mA, sA, axA, ayA);
    }
#undef PROC

    // merge the two chains
    float mF = fmaxf(mA, mB);
    float dA = (mA > -INFINITY) ? exp2f(mA - mF) : 0.f;
    float dB = (mB > -INFINITY) ? exp2f(mB - mF) : 0.f;
    float s = sA * dA + sB * dB;
    float ax = axA * dA + axB * dB;
    float ay = ayA * dA + ayB * dB;
    float inv = 1.f / (s + 1e-9f);
    *outp = make_float2(ax * inv, ay * inv);
}

// ---------------- MLP head: relu(H@W1+b1)@W2 + b2 via MFMA ------------------
__global__ __launch_bounds__(256) void mlp_kernel(const float* __restrict__ H,
                                                  const _Float16* __restrict__ W16,
                                                  const float* __restrict__ b1,
                                                  const float* __restrict__ W2,
                                                  const float* __restrict__ b2,
                                                  float* __restrict__ out, int n) {
    __shared__ _Float16 sA[64 * 136];
    int t = threadIdx.x;
    int row0 = blockIdx.x * 64;
#pragma unroll
    for (int p = 0; p < 8; p++) {
        int f = p * 256 + t;
        int r = f >> 5, c4 = (f & 31) * 4;
        int gr = min(row0 + r, n - 1);
        float4 v = *reinterpret_cast<const float4*>(H + (size_t)gr * DM + c4);
        f16x4 h = {(_Float16)v.x, (_Float16)v.y, (_Float16)v.z, (_Float16)v.w};
        *reinterpret_cast<f16x4*>(&sA[r * 136 + c4]) = h;
    }
    __syncthreads();

    int w = t >> 6, l = t & 63;
    int lr = l & 15, lg = l >> 4;
    int rowb = w * 16;

    f32x4v acc[8];
#pragma unroll
    for (int nb = 0; nb < 8; nb++) acc[nb] = (f32x4v){0.f, 0.f, 0.f, 0.f};

#pragma unroll
    for (int kb = 0; kb < 4; kb++) {
        f16x8 a = *reinterpret_cast<const f16x8*>(&sA[(rowb + lr) * 136 + kb * 32 + lg * 8]);
#pragma unroll
        for (int nb = 0; nb < 8; nb++) {
            f16x8 b = *reinterpret_cast<const f16x8*>(&W16[((kb * 8 + nb) * 64 + l) * 8]);
            acc[nb] = __builtin_amdgcn_mfma_f32_16x16x32_f16(a, b, acc[nb], 0, 0, 0);
        }
    }

    float part[4] = {0.f, 0.f, 0.f, 0.f};
#pragma unroll
    for (int nb = 0; nb < 8; nb++) {
        int c = nb * 16 + lr;
        float b1v = b1[c];
        float w2v = W2[c];
#pragma unroll
        for (int i = 0; i < 4; i++) {
            float z = fmaxf(acc[nb][i] + b1v, 0.f);
            part[i] += z * w2v;
        }
    }
    float b2v = b2[0];
#pragma unroll
    for (int i = 0; i < 4; i++) {
        part[i] += __shfl_xor(part[i], 1, 64);
        part[i] += __shfl_xor(part[i], 2, 64);
        part[i] += __shfl_xor(part[i], 4, 64);
        part[i] += __shfl_xor(part[i], 8, 64);
        int r = row0 + rowb + lg * 4 + i;
        if (lr == 0 && r < n) out[r] = part[i] + b2v;
    }
}

// ---------------------------------------------------------------------------
extern "C" void kernel_launch(void* const* d_in, const int* in_sizes, int n_in,
                              void* d_out, int out_size, void* d_ws, size_t ws_size,
                              hipStream_t stream) {
    const float* X    = (const float*)d_in[0];
    const float* Seed = (const float*)d_in[1];
    const float* Dg   = (const float*)d_in[2];
    const float* Cl   = (const float*)d_in[3];
    const int* esrc   = (const int*)d_in[4];
    const int* edst   = (const int*)d_in[5];
    const float* Wseed = (const float*)d_in[6];
    const float* Wdeg  = (const float*)d_in[7];
    const float* Wclu  = (const float*)d_in[8];
    const float* Wq = (const float*)d_in[9];
    const float* Wk = (const float*)d_in[10];
    const float* Wv = (const float*)d_in[11];
    const float* Wo = (const float*)d_in[12];
    const float* W1 = (const float*)d_in[13];
    const float* b1 = (const float*)d_in[14];
    const float* W2 = (const float*)d_in[15];
    const float* b2 = (const float*)d_in[16];
    float* out = (float*)d_out;

    int n = in_sizes[0];
    int E = in_sizes[4];

    char* p = (char*)d_ws;
    auto alloc = [&](size_t bytes) {
        void* r = (void*)p;
        p += (bytes + 255) & ~(size_t)255;
        return r;
    };
    float* hbuf  = (float*)alloc((size_t)n * DM * 4);                  // h (fp32)
    float* qbuf  = (float*)alloc((size_t)n * DM * 4);                  // q (fp32)
    float* abuf  = (float*)alloc((size_t)n * DM * 4);                  // agg (fp32)
    unsigned short* kvbuf = (unsigned short*)alloc((size_t)n * 256 * 2);  // fp16 K|V
    _Float16* W16 = (_Float16*)alloc((size_t)13 * WSTRIDE * 2);        // packed weights
    int* deg    = (int*)alloc((size_t)n * 4);
    int* ptr    = (int*)alloc((size_t)(n + 1) * 4);
    int* ptrtmp = (int*)alloc((size_t)n * 4);
    int* bsums  = (int*)alloc(1024);
    int* fill   = (int*)alloc((size_t)n * 4);
    int* esrcs  = (int*)alloc((size_t)E * 4);
    (void)ws_size; (void)n_in; (void)out_size;

    hipMemsetAsync(deg, 0, (size_t)n * 4, stream);
    hipMemsetAsync(fill, 0, (size_t)n * 4, stream);

    {
        int total = n * (DM / 4);
        embed_kernel<<<(total + 255) / 256, 256, 0, stream>>>(X, Seed, Dg, Cl, Wseed, Wdeg,
                                                              Wclu, hbuf, n);
    }
    int nb = (n + 255) / 256;
    count_kernel<<<(E + 255) / 256, 256, 0, stream>>>(edst, deg, E);
    scan1_kernel<<<nb, 256, 0, stream>>>(deg, ptrtmp, bsums, n);
    scan2_kernel<<<1, 256, 0, stream>>>(bsums, nb);
    scan3_kernel<<<nb, 256, 0, stream>>>(ptrtmp, bsums, ptr, n);
    scatter_kernel<<<(E + 255) / 256, 256, 0, stream>>>(esrc, edst, ptr, fill, esrcs, E);

    prepack_kernel<<<dim3(4, 8, 13), 64, 0, stream>>>(Wq, Wk, Wv, Wo, W1, W16);

    int ggrid = (n + 63) / 64;
    int agrid = (n + 3) / 4;
    for (int i = 0; i < 3; i++) {
        const _Float16* wq16 = W16 + (size_t)(0 + i) * WSTRIDE;
        const _Float16* wk16 = W16 + (size_t)(3 + i) * WSTRIDE;
        const _Float16* wv16 = W16 + (size_t)(6 + i) * WSTRIDE;
        const _Float16* wo16 = W16 + (size_t)(9 + i) * WSTRIDE;
        gemm_mfma_kernel<0><<<ggrid, 256, 0, stream>>>(hbuf, wq16, qbuf, DM, 0, n);
        gemm_mfma_kernel<1><<<ggrid, 256, 0, stream>>>(hbuf, wk16, kvbuf, 256, 0, n);
        gemm_mfma_kernel<1><<<ggrid, 256, 0, stream>>>(hbuf, wv16, kvbuf, 256, 128, n);
        attn_kernel<<<agrid, 256, 0, stream>>>(qbuf, (const uint32_t*)kvbuf, ptr, esrcs,
                                               abuf, n);
        gemm_mfma_kernel<0><<<ggrid, 256, 0, stream>>>(abuf, wo16, hbuf, DM, 0, n);
    }
    mlp_kernel<<<ggrid, 256, 0, stream>>>(hbuf, W16 + (size_t)12 * WSTRIDE, b1, W2, b2, out, n);
}

// Round 7
// 716.900 us; speedup vs baseline: 2.2621x; 1.1368x over previous
//
#include <hip/hip_runtime.h>
#include <math.h>

#define DM 128            // d_model
#define HEADS 4
#define DH 32             // d_head
#define WSTRIDE 16384     // 128x128 fp16 elements per packed weight matrix

typedef _Float16 f16x8 __attribute__((ext_vector_type(8)));
typedef _Float16 f16x4 __attribute__((ext_vector_type(4)));
typedef _Float16 f16x2 __attribute__((ext_vector_type(2)));
typedef float f32x4v __attribute__((ext_vector_type(4)));

// DPP quad-perm butterfly adds (4-lane reduce, no DS ops)
__device__ __forceinline__ float dpp_xor1_add(float x) {
    int r = __builtin_amdgcn_update_dpp(0, __builtin_bit_cast(int, x), 0xB1, 0xf, 0xf, true);
    return x + __builtin_bit_cast(float, r);
}
__device__ __forceinline__ float dpp_xor2_add(float x) {
    int r = __builtin_amdgcn_update_dpp(0, __builtin_bit_cast(int, x), 0x4E, 0xf, 0xf, true);
    return x + __builtin_bit_cast(float, r);
}

// ---------------- embed: h = X + Seed*Wseed + D*Wdeg + C*Wclu ---------------
__global__ void embed_kernel(const float* __restrict__ X, const float* __restrict__ Seed,
                             const float* __restrict__ Dg, const float* __restrict__ Cl,
                             const float* __restrict__ Wseed, const float* __restrict__ Wdeg,
                             const float* __restrict__ Wclu, float* __restrict__ H, int n) {
    int i = blockIdx.x * blockDim.x + threadIdx.x;
    if (i >= n * (DM / 4)) return;
    int nd = i >> 5, d4 = (i & 31) * 4;
    float x = X[nd], sd = Seed[nd], dg = Dg[nd], cl = Cl[nd];
    float4 ws = *reinterpret_cast<const float4*>(Wseed + d4);
    float4 wd = *reinterpret_cast<const float4*>(Wdeg + d4);
    float4 wc = *reinterpret_cast<const float4*>(Wclu + d4);
    float4 o;
    o.x = x + sd * ws.x + dg * wd.x + cl * wc.x;
    o.y = x + sd * ws.y + dg * wd.y + cl * wc.y;
    o.z = x + sd * ws.z + dg * wd.z + cl * wc.z;
    o.w = x + sd * ws.w + dg * wd.w + cl * wc.w;
    *reinterpret_cast<float4*>(H + nd * DM + d4) = o;
}

// ---------------- CSR build -------------------------------------------------
__global__ void count_kernel(const int* __restrict__ edst, int* __restrict__ deg, int E) {
    int e = blockIdx.x * blockDim.x + threadIdx.x;
    if (e < E) atomicAdd(&deg[edst[e]], 1);
}

__global__ void scan1_kernel(const int* __restrict__ in, int* __restrict__ outv,
                             int* __restrict__ bsums, int n) {
    __shared__ int s[256];
    int t = threadIdx.x;
    int i = blockIdx.x * 256 + t;
    int v = (i < n) ? in[i] : 0;
    s[t] = v;
    __syncthreads();
    for (int off = 1; off < 256; off <<= 1) {
        int x = (t >= off) ? s[t - off] : 0;
        __syncthreads();
        s[t] += x;
        __syncthreads();
    }
    if (i < n) outv[i] = s[t];
    if (t == 255) bsums[blockIdx.x] = s[255];
}

__global__ void scan2_kernel(int* __restrict__ bsums, int nb) {
    __shared__ int s[256];
    int t = threadIdx.x;
    int v = (t < nb) ? bsums[t] : 0;
    s[t] = v;
    __syncthreads();
    for (int off = 1; off < 256; off <<= 1) {
        int x = (t >= off) ? s[t - off] : 0;
        __syncthreads();
        s[t] += x;
        __syncthreads();
    }
    if (t < nb) bsums[t] = s[t];
}

__global__ void scan3_kernel(const int* __restrict__ outv, const int* __restrict__ bsums,
                             int* __restrict__ ptr, int n) {
    int i = blockIdx.x * 256 + threadIdx.x;
    if (i == 0) ptr[0] = 0;
    if (i < n) {
        int add = (blockIdx.x > 0) ? bsums[blockIdx.x - 1] : 0;
        ptr[i + 1] = outv[i] + add;
    }
}

__global__ void scatter_kernel(const int* __restrict__ esrc, const int* __restrict__ edst,
                               const int* __restrict__ ptr, int* __restrict__ fill,
                               int* __restrict__ out, int E) {
    int e = blockIdx.x * blockDim.x + threadIdx.x;
    if (e >= E) return;
    int d = edst[e];
    int pos = ptr[d] + atomicAdd(&fill[d], 1);
    out[pos] = esrc[e];
}

// ---------------- W prepack: fp32 [128x128] -> fp16 MFMA-fragment order -----
__global__ void prepack_kernel(const float* __restrict__ Wq, const float* __restrict__ Wk,
                               const float* __restrict__ Wv, const float* __restrict__ Wo,
                               const float* __restrict__ W1, _Float16* __restrict__ W16) {
    int m = blockIdx.z;
    const float* W;
    if (m < 3)       W = Wq + (size_t)m * DM * DM;
    else if (m < 6)  W = Wk + (size_t)(m - 3) * DM * DM;
    else if (m < 9)  W = Wv + (size_t)(m - 6) * DM * DM;
    else if (m < 12) W = Wo + (size_t)(m - 9) * DM * DM;
    else             W = W1;
    int kb = blockIdx.x, nb = blockIdx.y, l = threadIdx.x;
    int kbase = kb * 32 + (l >> 4) * 8;
    int c = nb * 16 + (l & 15);
    f16x8 v;
#pragma unroll
    for (int j = 0; j < 8; j++) v[j] = (_Float16)W[(kbase + j) * DM + c];
    *reinterpret_cast<f16x8*>(W16 + (size_t)m * WSTRIDE + ((kb * 8 + nb) * 64 + l) * 8) = v;
}

// ---------------- MFMA GEMM (unchanged from R6) -----------------------------
template <int OUT>
__global__ __launch_bounds__(256) void gemm_mfma_kernel(const float* __restrict__ A,
                                                        const _Float16* __restrict__ W16,
                                                        void* __restrict__ O, int ldO,
                                                        int colOff, int n) {
    __shared__ _Float16 sA[64 * 136];
    int t = threadIdx.x;
    int row0 = blockIdx.x * 64;
#pragma unroll
    for (int p = 0; p < 8; p++) {
        int f = p * 256 + t;
        int r = f >> 5, c4 = (f & 31) * 4;
        int gr = min(row0 + r, n - 1);
        float4 v = *reinterpret_cast<const float4*>(A + (size_t)gr * DM + c4);
        f16x4 h = {(_Float16)v.x, (_Float16)v.y, (_Float16)v.z, (_Float16)v.w};
        *reinterpret_cast<f16x4*>(&sA[r * 136 + c4]) = h;
    }
    __syncthreads();

    int w = t >> 6, l = t & 63;
    int lr = l & 15, lg = l >> 4;
    int rowb = w * 16;

    f32x4v acc[8];
#pragma unroll
    for (int nb = 0; nb < 8; nb++) acc[nb] = (f32x4v){0.f, 0.f, 0.f, 0.f};

#pragma unroll
    for (int kb = 0; kb < 4; kb++) {
        f16x8 a = *reinterpret_cast<const f16x8*>(&sA[(rowb + lr) * 136 + kb * 32 + lg * 8]);
#pragma unroll
        for (int nb = 0; nb < 8; nb++) {
            f16x8 b = *reinterpret_cast<const f16x8*>(&W16[((kb * 8 + nb) * 64 + l) * 8]);
            acc[nb] = __builtin_amdgcn_mfma_f32_16x16x32_f16(a, b, acc[nb], 0, 0, 0);
        }
    }

#pragma unroll
    for (int nb = 0; nb < 8; nb++) {
#pragma unroll
        for (int i = 0; i < 4; i++) {
            int r = row0 + rowb + lg * 4 + i;
            if (r >= n) continue;
            int c = nb * 16 + lr;
            if (OUT == 0) {
                ((float*)O)[(size_t)r * ldO + c] = acc[nb][i];
            } else {
                _Float16 h = (_Float16)acc[nb][i];
                ((unsigned short*)O)[(size_t)r * ldO + colOff + c] =
                    __builtin_bit_cast(unsigned short, h);
            }
        }
    }
}

// ---------------- attention v3: wave = dst node, 4 edges/iter ---------------
// lane: quarter q4 = lane>>4 (chain id, 1 edge of the 4), w = lane&15 holds
// dims [8w, 8w+8). Head h = w>>2 -> reduce over 4 lanes via DPP quad-perm.
// Defer-max online softmax in exp2 space (THR=8). KV row: [128 f16 k][128 f16 v].
__global__ __launch_bounds__(256) void attn_kernel(const float* __restrict__ Q,
                                                   const uint32_t* __restrict__ KV,
                                                   const int* __restrict__ ptr,
                                                   const int* __restrict__ esrc,
                                                   float* __restrict__ AGG, int n) {
    int wv = threadIdx.x >> 6;
    int lane = threadIdx.x & 63;
    int node = blockIdx.x * 4 + wv;
    if (node >= n) return;
    int e0 = ptr[node], e1 = ptr[node + 1];
    int q4 = lane >> 4;
    int w = lane & 15;
    float* outbase = AGG + (size_t)node * DM + 8 * w;
    if (e0 >= e1) {
        if (lane < 16) {
            *reinterpret_cast<float4*>(outbase) = make_float4(0.f, 0.f, 0.f, 0.f);
            *reinterpret_cast<float4*>(outbase + 4) = make_float4(0.f, 0.f, 0.f, 0.f);
        }
        return;
    }
    // pre-scale q by 1/sqrt(32)*log2(e): exp2-softmax == exp-softmax exactly
    const float scale = 0.17677669529663687f * 1.4426950408889634f;
    float4 qa = *reinterpret_cast<const float4*>(Q + (size_t)node * DM + 8 * w);
    float4 qb = *reinterpret_cast<const float4*>(Q + (size_t)node * DM + 8 * w + 4);
    f16x2 qh0 = {(_Float16)(qa.x * scale), (_Float16)(qa.y * scale)};
    f16x2 qh1 = {(_Float16)(qa.z * scale), (_Float16)(qa.w * scale)};
    f16x2 qh2 = {(_Float16)(qb.x * scale), (_Float16)(qb.y * scale)};
    f16x2 qh3 = {(_Float16)(qb.z * scale), (_Float16)(qb.w * scale)};

    float m = -1e30f, s = 0.f;
    float a0 = 0.f, a1 = 0.f, a2 = 0.f, a3 = 0.f, a4 = 0.f, a5 = 0.f, a6 = 0.f, a7 = 0.f;

    int last = e1 - 1;
    int niter = (e1 - e0 + 3) >> 2;        // 4 edges per iteration
    int niter2 = (niter + 1) >> 1;         // 2x-unrolled pairs (pads absorb)

    const uint32_t* kvw = KV + w * 4;      // lane's 16B k-slot; v at +64 u32

    uint4 k0, v0, k1, v1;
    {
        int i0 = esrc[min(e0 + q4, last)];
        const uint32_t* r0 = kvw + (size_t)i0 * 128;
        k0 = *reinterpret_cast<const uint4*>(r0);
        v0 = *reinterpret_cast<const uint4*>(r0 + 64);
        int i1 = esrc[min(e0 + 4 + q4, last)];
        const uint32_t* r1 = kvw + (size_t)i1 * 128;
        k1 = *reinterpret_cast<const uint4*>(r1);
        v1 = *reinterpret_cast<const uint4*>(r1 + 64);
    }
    int idx2 = esrc[min(e0 + 8 + q4, last)];

#define APROC(kc, vc, bidx)                                                            \
    {                                                                                  \
        float p = __builtin_amdgcn_fdot2(qh0, __builtin_bit_cast(f16x2, (kc).x), 0.f, false); \
        p = __builtin_amdgcn_fdot2(qh1, __builtin_bit_cast(f16x2, (kc).y), p, false);  \
        p = __builtin_amdgcn_fdot2(qh2, __builtin_bit_cast(f16x2, (kc).z), p, false);  \
        p = __builtin_amdgcn_fdot2(qh3, __builtin_bit_cast(f16x2, (kc).w), p, false);  \
        p = dpp_xor1_add(p);                                                           \
        p = dpp_xor2_add(p);                                                           \
        p = ((bidx) < e1) ? p : -3.0e38f;                                              \
        float diff = p - m;                                                            \
        if (__any(diff > 8.f)) {                                                       \
            float mn = fmaxf(m, p);                                                    \
            float dd = exp2f(m - mn);                                                  \
            s *= dd;                                                                   \
            a0 *= dd; a1 *= dd; a2 *= dd; a3 *= dd;                                    \
            a4 *= dd; a5 *= dd; a6 *= dd; a7 *= dd;                                    \
            m = mn;                                                                    \
            diff = p - m;                                                              \
        }                                                                              \
        float wg = exp2f(diff);                                                        \
        s += wg;                                                                       \
        f16x2 vh0 = __builtin_bit_cast(f16x2, (vc).x);                                 \
        f16x2 vh1 = __builtin_bit_cast(f16x2, (vc).y);                                 \
        f16x2 vh2 = __builtin_bit_cast(f16x2, (vc).z);                                 \
        f16x2 vh3 = __builtin_bit_cast(f16x2, (vc).w);                                 \
        a0 += wg * (float)vh0[0]; a1 += wg * (float)vh0[1];                            \
        a2 += wg * (float)vh1[0]; a3 += wg * (float)vh1[1];                            \
        a4 += wg * (float)vh2[0]; a5 += wg * (float)vh2[1];                            \
        a6 += wg * (float)vh3[0]; a7 += wg * (float)vh3[1];                            \
    }

    int b = e0 + q4;   // this lane's edge index for the current iteration
    for (int it = 0; it < niter2; it++) {
        // sub-iter A: consume (k0,v0); prefetch data for iter i+2 into (k0,v0)
        {
            uint4 kc = k0, vc = v0;
            const uint32_t* r = kvw + (size_t)idx2 * 128;
            k0 = *reinterpret_cast<const uint4*>(r);
            v0 = *reinterpret_cast<const uint4*>(r + 64);
            idx2 = esrc[min(b + 12, last)];
            APROC(kc, vc, b);
            b += 4;
        }
        // sub-iter B: consume (k1,v1); prefetch data for iter i+3 into (k1,v1)
        {
            uint4 kc = k1, vc = v1;
            const uint32_t* r = kvw + (size_t)idx2 * 128;
            k1 = *reinterpret_cast<const uint4*>(r);
            v1 = *reinterpret_cast<const uint4*>(r + 64);
            idx2 = esrc[min(b + 12, last)];
            APROC(kc, vc, b);
            b += 4;
        }
    }
#undef APROC

    // merge the 4 quarter-chains (exact for any m references)
#pragma unroll
    for (int off = 16; off <= 32; off <<= 1) {
        float m2 = __shfl_xor(m, off, 64);
        float s2 = __shfl_xor(s, off, 64);
        float b0 = __shfl_xor(a0, off, 64), b1 = __shfl_xor(a1, off, 64);
        float b2 = __shfl_xor(a2, off, 64), b3 = __shfl_xor(a3, off, 64);
        float b4 = __shfl_xor(a4, off, 64), b5 = __shfl_xor(a5, off, 64);
        float b6 = __shfl_xor(a6, off, 64), b7 = __shfl_xor(a7, off, 64);
        float mF = fmaxf(m, m2);
        float d1 = exp2f(m - mF), d2 = exp2f(m2 - mF);
        s = s * d1 + s2 * d2;
        a0 = a0 * d1 + b0 * d2; a1 = a1 * d1 + b1 * d2;
        a2 = a2 * d1 + b2 * d2; a3 = a3 * d1 + b3 * d2;
        a4 = a4 * d1 + b4 * d2; a5 = a5 * d1 + b5 * d2;
        a6 = a6 * d1 + b6 * d2; a7 = a7 * d1 + b7 * d2;
        m = mF;
    }

    float inv = 1.f / (s + 1e-9f);
    if (lane < 16) {
        *reinterpret_cast<float4*>(outbase) =
            make_float4(a0 * inv, a1 * inv, a2 * inv, a3 * inv);
        *reinterpret_cast<float4*>(outbase + 4) =
            make_float4(a4 * inv, a5 * inv, a6 * inv, a7 * inv);
    }
}

// ---------------- MLP head (unchanged from R6) ------------------------------
__global__ __launch_bounds__(256) void mlp_kernel(const float* __restrict__ H,
                                                  const _Float16* __restrict__ W16,
                                                  const float* __restrict__ b1,
                                                  const float* __restrict__ W2,
                                                  const float* __restrict__ b2,
                                                  float* __restrict__ out, int n) {
    __shared__ _Float16 sA[64 * 136];
    int t = threadIdx.x;
    int row0 = blockIdx.x * 64;
#pragma unroll
    for (int p = 0; p < 8; p++) {
        int f = p * 256 + t;
        int r = f >> 5, c4 = (f & 31) * 4;
        int gr = min(row0 + r, n - 1);
        float4 v = *reinterpret_cast<const float4*>(H + (size_t)gr * DM + c4);
        f16x4 h = {(_Float16)v.x, (_Float16)v.y, (_Float16)v.z, (_Float16)v.w};
        *reinterpret_cast<f16x4*>(&sA[r * 136 + c4]) = h;
    }
    __syncthreads();

    int w = t >> 6, l = t & 63;
    int lr = l & 15, lg = l >> 4;
    int rowb = w * 16;

    f32x4v acc[8];
#pragma unroll
    for (int nb = 0; nb < 8; nb++) acc[nb] = (f32x4v){0.f, 0.f, 0.f, 0.f};

#pragma unroll
    for (int kb = 0; kb < 4; kb++) {
        f16x8 a = *reinterpret_cast<const f16x8*>(&sA[(rowb + lr) * 136 + kb * 32 + lg * 8]);
#pragma unroll
        for (int nb = 0; nb < 8; nb++) {
            f16x8 b = *reinterpret_cast<const f16x8*>(&W16[((kb * 8 + nb) * 64 + l) * 8]);
            acc[nb] = __builtin_amdgcn_mfma_f32_16x16x32_f16(a, b, acc[nb], 0, 0, 0);
        }
    }

    float part[4] = {0.f, 0.f, 0.f, 0.f};
#pragma unroll
    for (int nb = 0; nb < 8; nb++) {
        int c = nb * 16 + lr;
        float b1v = b1[c];
        float w2v = W2[c];
#pragma unroll
        for (int i = 0; i < 4; i++) {
            float z = fmaxf(acc[nb][i] + b1v, 0.f);
            part[i] += z * w2v;
        }
    }
    float b2v = b2[0];
#pragma unroll
    for (int i = 0; i < 4; i++) {
        part[i] += __shfl_xor(part[i], 1, 64);
        part[i] += __shfl_xor(part[i], 2, 64);
        part[i] += __shfl_xor(part[i], 4, 64);
        part[i] += __shfl_xor(part[i], 8, 64);
        int r = row0 + rowb + lg * 4 + i;
        if (lr == 0 && r < n) out[r] = part[i] + b2v;
    }
}

// ---------------------------------------------------------------------------
extern "C" void kernel_launch(void* const* d_in, const int* in_sizes, int n_in,
                              void* d_out, int out_size, void* d_ws, size_t ws_size,
                              hipStream_t stream) {
    const float* X    = (const float*)d_in[0];
    const float* Seed = (const float*)d_in[1];
    const float* Dg   = (const float*)d_in[2];
    const float* Cl   = (const float*)d_in[3];
    const int* esrc   = (const int*)d_in[4];
    const int* edst   = (const int*)d_in[5];
    const float* Wseed = (const float*)d_in[6];
    const float* Wdeg  = (const float*)d_in[7];
    const float* Wclu  = (const float*)d_in[8];
    const float* Wq = (const float*)d_in[9];
    const float* Wk = (const float*)d_in[10];
    const float* Wv = (const float*)d_in[11];
    const float* Wo = (const float*)d_in[12];
    const float* W1 = (const float*)d_in[13];
    const float* b1 = (const float*)d_in[14];
    const float* W2 = (const float*)d_in[15];
    const float* b2 = (const float*)d_in[16];
    float* out = (float*)d_out;

    int n = in_sizes[0];
    int E = in_sizes[4];

    char* p = (char*)d_ws;
    auto alloc = [&](size_t bytes) {
        void* r = (void*)p;
        p += (bytes + 255) & ~(size_t)255;
        return r;
    };
    float* hbuf  = (float*)alloc((size_t)n * DM * 4);                  // h (fp32)
    float* qbuf  = (float*)alloc((size_t)n * DM * 4);                  // q (fp32)
    float* abuf  = (float*)alloc((size_t)n * DM * 4);                  // agg (fp32)
    unsigned short* kvbuf = (unsigned short*)alloc((size_t)n * 256 * 2);  // fp16 K|V
    _Float16* W16 = (_Float16*)alloc((size_t)13 * WSTRIDE * 2);        // packed weights
    int* deg    = (int*)alloc((size_t)n * 4);
    int* ptr    = (int*)alloc((size_t)(n + 1) * 4);
    int* ptrtmp = (int*)alloc((size_t)n * 4);
    int* bsums  = (int*)alloc(1024);
    int* fill   = (int*)alloc((size_t)n * 4);
    int* esrcs  = (int*)alloc((size_t)E * 4);
    (void)ws_size; (void)n_in; (void)out_size;

    hipMemsetAsync(deg, 0, (size_t)n * 4, stream);
    hipMemsetAsync(fill, 0, (size_t)n * 4, stream);

    {
        int total = n * (DM / 4);
        embed_kernel<<<(total + 255) / 256, 256, 0, stream>>>(X, Seed, Dg, Cl, Wseed, Wdeg,
                                                              Wclu, hbuf, n);
    }
    int nb = (n + 255) / 256;
    count_kernel<<<(E + 255) / 256, 256, 0, stream>>>(edst, deg, E);
    scan1_kernel<<<nb, 256, 0, stream>>>(deg, ptrtmp, bsums, n);
    scan2_kernel<<<1, 256, 0, stream>>>(bsums, nb);
    scan3_kernel<<<nb, 256, 0, stream>>>(ptrtmp, bsums, ptr, n);
    scatter_kernel<<<(E + 255) / 256, 256, 0, stream>>>(esrc, edst, ptr, fill, esrcs, E);

    prepack_kernel<<<dim3(4, 8, 13), 64, 0, stream>>>(Wq, Wk, Wv, Wo, W1, W16);

    int ggrid = (n + 63) / 64;
    int agrid = (n + 3) / 4;
    for (int i = 0; i < 3; i++) {
        const _Float16* wq16 = W16 + (size_t)(0 + i) * WSTRIDE;
        const _Float16* wk16 = W16 + (size_t)(3 + i) * WSTRIDE;
        const _Float16* wv16 = W16 + (size_t)(6 + i) * WSTRIDE;
        const _Float16* wo16 = W16 + (size_t)(9 + i) * WSTRIDE;
        gemm_mfma_kernel<0><<<ggrid, 256, 0, stream>>>(hbuf, wq16, qbuf, DM, 0, n);
        gemm_mfma_kernel<1><<<ggrid, 256, 0, stream>>>(hbuf, wk16, kvbuf, 256, 0, n);
        gemm_mfma_kernel<1><<<ggrid, 256, 0, stream>>>(hbuf, wv16, kvbuf, 256, 128, n);
        attn_kernel<<<agrid, 256, 0, stream>>>(qbuf, (const uint32_t*)kvbuf, ptr, esrcs,
                                               abuf, n);
        gemm_mfma_kernel<0><<<ggrid, 256, 0, stream>>>(abuf, wo16, hbuf, DM, 0, n);
    }
    mlp_kernel<<<ggrid, 256, 0, stream>>>(hbuf, W16 + (size_t)12 * WSTRIDE, b1, W2, b2, out, n);
}

// Round 9
// 670.654 us; speedup vs baseline: 2.4181x; 1.0690x over previous
//
#include <hip/hip_runtime.h>
#include <math.h>

#define DM 128            // d_model
#define HEADS 4
#define DH 32             // d_head
#define WSTRIDE 16384     // 128x128 fp16 elements per packed weight matrix

typedef _Float16 f16x8 __attribute__((ext_vector_type(8)));
typedef _Float16 f16x4 __attribute__((ext_vector_type(4)));
typedef _Float16 f16x2 __attribute__((ext_vector_type(2)));
typedef float f32x4v __attribute__((ext_vector_type(4)));

// DPP quad-perm butterfly adds (4-lane reduce, no DS ops)
__device__ __forceinline__ float dpp_xor1_add(float x) {
    int r = __builtin_amdgcn_update_dpp(0, __builtin_bit_cast(int, x), 0xB1, 0xf, 0xf, true);
    return x + __builtin_bit_cast(float, r);
}
__device__ __forceinline__ float dpp_xor2_add(float x) {
    int r = __builtin_amdgcn_update_dpp(0, __builtin_bit_cast(int, x), 0x4E, 0xf, 0xf, true);
    return x + __builtin_bit_cast(float, r);
}
__device__ __forceinline__ uint32_t pkh(float x, float y) {
    f16x2 h = {(_Float16)x, (_Float16)y};
    return __builtin_bit_cast(uint32_t, h);
}

// ---------------- CSR build -------------------------------------------------
__global__ void count_kernel(const int* __restrict__ edst, int* __restrict__ deg, int E) {
    int e = blockIdx.x * blockDim.x + threadIdx.x;
    if (e < E) atomicAdd(&deg[edst[e]], 1);
}

__global__ void scan1_kernel(const int* __restrict__ in, int* __restrict__ outv,
                             int* __restrict__ bsums, int n) {
    __shared__ int s[256];
    int t = threadIdx.x;
    int i = blockIdx.x * 256 + t;
    int v = (i < n) ? in[i] : 0;
    s[t] = v;
    __syncthreads();
    for (int off = 1; off < 256; off <<= 1) {
        int x = (t >= off) ? s[t - off] : 0;
        __syncthreads();
        s[t] += x;
        __syncthreads();
    }
    if (i < n) outv[i] = s[t];
    if (t == 255) bsums[blockIdx.x] = s[255];
}

__global__ void scan2_kernel(int* __restrict__ bsums, int nb) {
    __shared__ int s[256];
    int t = threadIdx.x;
    int v = (t < nb) ? bsums[t] : 0;
    s[t] = v;
    __syncthreads();
    for (int off = 1; off < 256; off <<= 1) {
        int x = (t >= off) ? s[t - off] : 0;
        __syncthreads();
        s[t] += x;
        __syncthreads();
    }
    if (t < nb) bsums[t] = s[t];
}

__global__ void scan3_kernel(const int* __restrict__ outv, const int* __restrict__ bsums,
                             int* __restrict__ ptr, int n) {
    int i = blockIdx.x * 256 + threadIdx.x;
    if (i == 0) ptr[0] = 0;
    if (i < n) {
        int add = (blockIdx.x > 0) ? bsums[blockIdx.x - 1] : 0;
        ptr[i + 1] = outv[i] + add;
    }
}

__global__ void scatter_kernel(const int* __restrict__ esrc, const int* __restrict__ edst,
                               const int* __restrict__ ptr, int* __restrict__ fill,
                               int* __restrict__ out, int E) {
    int e = blockIdx.x * blockDim.x + threadIdx.x;
    if (e >= E) return;
    int d = edst[e];
    int pos = ptr[d] + atomicAdd(&fill[d], 1);
    out[pos] = esrc[e];
}

// ---------------- W prepack: fp32 [128x128] -> fp16 MFMA-fragment order -----
// frag: ((kb*8+nb)*64 + lane)*8 + j <=> W[kb*32+(lane>>4)*8+j][nb*16+(lane&15)]
// matrices: 0..2 Wq, 3..5 Wk, 6..8 Wv, 9..11 Wo, 12 W1
__global__ void prepack_kernel(const float* __restrict__ Wq, const float* __restrict__ Wk,
                               const float* __restrict__ Wv, const float* __restrict__ Wo,
                               const float* __restrict__ W1, _Float16* __restrict__ W16) {
    int m = blockIdx.z;
    const float* W;
    if (m < 3)       W = Wq + (size_t)m * DM * DM;
    else if (m < 6)  W = Wk + (size_t)(m - 3) * DM * DM;
    else if (m < 9)  W = Wv + (size_t)(m - 6) * DM * DM;
    else if (m < 12) W = Wo + (size_t)(m - 9) * DM * DM;
    else             W = W1;
    int kb = blockIdx.x, nb = blockIdx.y, l = threadIdx.x;
    int kbase = kb * 32 + (l >> 4) * 8;
    int c = nb * 16 + (l & 15);
    f16x8 v;
#pragma unroll
    for (int j = 0; j < 8; j++) v[j] = (_Float16)W[(kbase + j) * DM + c];
    *reinterpret_cast<f16x8*>(W16 + (size_t)m * WSTRIDE + ((kb * 8 + nb) * 64 + l) * 8) = v;
}

// ---------------- shared tile-GEMM helpers ----------------------------------
// acc[nb][i] = out[row0+rowb+lg*4+i][nb*16+lr] ; A-frag row = rowb+lr
__device__ __forceinline__ void tile_gemm(const _Float16* __restrict__ sRow,
                                          const _Float16* __restrict__ W16, int lg, int l,
                                          f32x4v acc[8]) {
#pragma unroll
    for (int nb = 0; nb < 8; nb++) acc[nb] = (f32x4v){0.f, 0.f, 0.f, 0.f};
#pragma unroll
    for (int kb = 0; kb < 4; kb++) {
        f16x8 a = *reinterpret_cast<const f16x8*>(sRow + kb * 32 + lg * 8);
#pragma unroll
        for (int nb = 0; nb < 8; nb++) {
            f16x8 b = *reinterpret_cast<const f16x8*>(&W16[((kb * 8 + nb) * 64 + l) * 8]);
            acc[nb] = __builtin_amdgcn_mfma_f32_16x16x32_f16(a, b, acc[nb], 0, 0, 0);
        }
    }
}

// compute q,k,v from sH (wave-private rows) and store fp16
__device__ __forceinline__ void qkv_store(const _Float16* __restrict__ sH, int rowb, int lr,
                                          int lg, int l, int row0, int n,
                                          const _Float16* __restrict__ Wq16,
                                          const _Float16* __restrict__ Wk16,
                                          const _Float16* __restrict__ Wv16,
                                          _Float16* __restrict__ Qo,
                                          _Float16* __restrict__ KVo) {
    const _Float16* sRow = sH + (rowb + lr) * 136;
    f32x4v acc[8];
    // Q
    tile_gemm(sRow, Wq16, lg, l, acc);
#pragma unroll
    for (int nb = 0; nb < 8; nb++)
#pragma unroll
        for (int i = 0; i < 4; i++) {
            int r = row0 + rowb + lg * 4 + i;
            if (r < n) Qo[(size_t)r * DM + nb * 16 + lr] = (_Float16)acc[nb][i];
        }
    // K
    tile_gemm(sRow, Wk16, lg, l, acc);
#pragma unroll
    for (int nb = 0; nb < 8; nb++)
#pragma unroll
        for (int i = 0; i < 4; i++) {
            int r = row0 + rowb + lg * 4 + i;
            if (r < n) KVo[(size_t)r * 256 + nb * 16 + lr] = (_Float16)acc[nb][i];
        }
    // V
    tile_gemm(sRow, Wv16, lg, l, acc);
#pragma unroll
    for (int nb = 0; nb < 8; nb++)
#pragma unroll
        for (int i = 0; i < 4; i++) {
            int r = row0 + rowb + lg * 4 + i;
            if (r < n) KVo[(size_t)r * 256 + 128 + nb * 16 + lr] = (_Float16)acc[nb][i];
        }
}

// ---------------- fused embed -> QKV ----------------------------------------
__global__ __launch_bounds__(256) void fused_embed_qkv_kernel(
    const float* __restrict__ X, const float* __restrict__ Seed,
    const float* __restrict__ Dg, const float* __restrict__ Cl,
    const float* __restrict__ Wseed, const float* __restrict__ Wdeg,
    const float* __restrict__ Wclu,
    const _Float16* __restrict__ Wq16, const _Float16* __restrict__ Wk16,
    const _Float16* __restrict__ Wv16,
    _Float16* __restrict__ Qo, _Float16* __restrict__ KVo, int n) {
    __shared__ _Float16 sH[64 * 136];
    int t = threadIdx.x;
    int row0 = blockIdx.x * 64;
    {
        int row = t >> 2, qt = t & 3;
        int gr = min(row0 + row, n - 1);
        float x = X[gr], sd = Seed[gr], dg = Dg[gr], cl = Cl[gr];
#pragma unroll
        for (int j = 0; j < 8; j++) {
            int c4 = qt * 32 + j * 4;
            float4 ws = *reinterpret_cast<const float4*>(Wseed + c4);
            float4 wd = *reinterpret_cast<const float4*>(Wdeg + c4);
            float4 wc = *reinterpret_cast<const float4*>(Wclu + c4);
            f16x4 h;
            h[0] = (_Float16)(x + sd * ws.x + dg * wd.x + cl * wc.x);
            h[1] = (_Float16)(x + sd * ws.y + dg * wd.y + cl * wc.y);
            h[2] = (_Float16)(x + sd * ws.z + dg * wd.z + cl * wc.z);
            h[3] = (_Float16)(x + sd * ws.w + dg * wd.w + cl * wc.w);
            *reinterpret_cast<f16x4*>(&sH[row * 136 + c4]) = h;
        }
    }
    __syncthreads();
    int w = t >> 6, l = t & 63;
    qkv_store(sH, w * 16, l & 15, l >> 4, l, row0, n, Wq16, Wk16, Wv16, Qo, KVo);
}

// ---------------- fused Wo -> QKV -------------------------------------------
__global__ __launch_bounds__(256) void fused_wo_qkv_kernel(
    const _Float16* __restrict__ Ain, const _Float16* __restrict__ Wo16,
    const _Float16* __restrict__ Wq16, const _Float16* __restrict__ Wk16,
    const _Float16* __restrict__ Wv16,
    _Float16* __restrict__ Qo, _Float16* __restrict__ KVo, int n) {
    __shared__ _Float16 sA[64 * 136];
    __shared__ _Float16 sH[64 * 136];
    int t = threadIdx.x;
    int row0 = blockIdx.x * 64;
#pragma unroll
    for (int p = 0; p < 4; p++) {
        int f = p * 256 + t;
        int r = f >> 4, c8 = (f & 15) * 8;
        int gr = min(row0 + r, n - 1);
        *reinterpret_cast<uint4*>(&sA[r * 136 + c8]) =
            *reinterpret_cast<const uint4*>(Ain + (size_t)gr * DM + c8);
    }
    __syncthreads();
    int w = t >> 6, l = t & 63;
    int lr = l & 15, lg = l >> 4;
    int rowb = w * 16;
    f32x4v acc[8];
    tile_gemm(sA + (rowb + lr) * 136, Wo16, lg, l, acc);
    // spill h (wave-private rows) to LDS fp16
#pragma unroll
    for (int nb = 0; nb < 8; nb++)
#pragma unroll
        for (int i = 0; i < 4; i++)
            sH[(rowb + lg * 4 + i) * 136 + nb * 16 + lr] = (_Float16)acc[nb][i];
    __syncthreads();
    qkv_store(sH, rowb, lr, lg, l, row0, n, Wq16, Wk16, Wv16, Qo, KVo);
}

// ---------------- fused Wo -> MLP head --------------------------------------
__global__ __launch_bounds__(256) void fused_wo_mlp_kernel(
    const _Float16* __restrict__ Ain, const _Float16* __restrict__ Wo16,
    const _Float16* __restrict__ W116, const float* __restrict__ b1,
    const float* __restrict__ W2, const float* __restrict__ b2,
    float* __restrict__ out, int n) {
    __shared__ _Float16 sA[64 * 136];
    __shared__ _Float16 sH[64 * 136];
    int t = threadIdx.x;
    int row0 = blockIdx.x * 64;
#pragma unroll
    for (int p = 0; p < 4; p++) {
        int f = p * 256 + t;
        int r = f >> 4, c8 = (f & 15) * 8;
        int gr = min(row0 + r, n - 1);
        *reinterpret_cast<uint4*>(&sA[r * 136 + c8]) =
            *reinterpret_cast<const uint4*>(Ain + (size_t)gr * DM + c8);
    }
    __syncthreads();
    int w = t >> 6, l = t & 63;
    int lr = l & 15, lg = l >> 4;
    int rowb = w * 16;
    f32x4v acc[8];
    tile_gemm(sA + (rowb + lr) * 136, Wo16, lg, l, acc);
#pragma unroll
    for (int nb = 0; nb < 8; nb++)
#pragma unroll
        for (int i = 0; i < 4; i++)
            sH[(rowb + lg * 4 + i) * 136 + nb * 16 + lr] = (_Float16)acc[nb][i];
    __syncthreads();
    tile_gemm(sH + (rowb + lr) * 136, W116, lg, l, acc);
    // epilogue: relu(acc + b1) dot W2, reduce over the 16 col-lanes
    float part[4] = {0.f, 0.f, 0.f, 0.f};
#pragma unroll
    for (int nb = 0; nb < 8; nb++) {
        int c = nb * 16 + lr;
        float b1v = b1[c];
        float w2v = W2[c];
#pragma unroll
        for (int i = 0; i < 4; i++) {
            float z = fmaxf(acc[nb][i] + b1v, 0.f);
            part[i] += z * w2v;
        }
    }
    float b2v = b2[0];
#pragma unroll
    for (int i = 0; i < 4; i++) {
        part[i] += __shfl_xor(part[i], 1, 64);
        part[i] += __shfl_xor(part[i], 2, 64);
        part[i] += __shfl_xor(part[i], 4, 64);
        part[i] += __shfl_xor(part[i], 8, 64);
        int r = row0 + rowb + lg * 4 + i;
        if (lr == 0 && r < n) out[r] = part[i] + b2v;
    }
}

// ---------------- attention: wave = dst node, 4 edges/iter, fp16 Q/KV/agg ---
__global__ __launch_bounds__(256) void attn_kernel(const _Float16* __restrict__ Q,
                                                   const uint32_t* __restrict__ KV,
                                                   const int* __restrict__ ptr,
                                                   const int* __restrict__ esrc,
                                                   _Float16* __restrict__ AGG, int n) {
    int wv = threadIdx.x >> 6;
    int lane = threadIdx.x & 63;
    int node = blockIdx.x * 4 + wv;
    if (node >= n) return;
    int e0 = ptr[node], e1 = ptr[node + 1];
    int q4 = lane >> 4;
    int w = lane & 15;
    _Float16* outbase = AGG + (size_t)node * DM + 8 * w;
    if (e0 >= e1) {
        if (lane < 16) *reinterpret_cast<uint4*>(outbase) = make_uint4(0, 0, 0, 0);
        return;
    }
    // 1/sqrt(32)*log2(e), applied post-reduce: exp2-softmax == exp-softmax
    const float scale = 0.17677669529663687f * 1.4426950408889634f;
    uint4 qv = *reinterpret_cast<const uint4*>(Q + (size_t)node * DM + 8 * w);
    f16x2 qh0 = __builtin_bit_cast(f16x2, qv.x);
    f16x2 qh1 = __builtin_bit_cast(f16x2, qv.y);
    f16x2 qh2 = __builtin_bit_cast(f16x2, qv.z);
    f16x2 qh3 = __builtin_bit_cast(f16x2, qv.w);

    float m = -1e30f, s = 0.f;
    float a0 = 0.f, a1 = 0.f, a2 = 0.f, a3 = 0.f, a4 = 0.f, a5 = 0.f, a6 = 0.f, a7 = 0.f;

    int last = e1 - 1;
    int niter = (e1 - e0 + 3) >> 2;
    int niter2 = (niter + 1) >> 1;

    const uint32_t* kvw = KV + w * 4;

    uint4 k0, v0, k1, v1;
    {
        int i0 = esrc[min(e0 + q4, last)];
        const uint32_t* r0 = kvw + (size_t)i0 * 128;
        k0 = *reinterpret_cast<const uint4*>(r0);
        v0 = *reinterpret_cast<const uint4*>(r0 + 64);
        int i1 = esrc[min(e0 + 4 + q4, last)];
        const uint32_t* r1 = kvw + (size_t)i1 * 128;
        k1 = *reinterpret_cast<const uint4*>(r1);
        v1 = *reinterpret_cast<const uint4*>(r1 + 64);
    }
    int idx2 = esrc[min(e0 + 8 + q4, last)];

#define APROC(kc, vc, bidx)                                                            \
    {                                                                                  \
        float p = __builtin_amdgcn_fdot2(qh0, __builtin_bit_cast(f16x2, (kc).x), 0.f, false); \
        p = __builtin_amdgcn_fdot2(qh1, __builtin_bit_cast(f16x2, (kc).y), p, false);  \
        p = __builtin_amdgcn_fdot2(qh2, __builtin_bit_cast(f16x2, (kc).z), p, false);  \
        p = __builtin_amdgcn_fdot2(qh3, __builtin_bit_cast(f16x2, (kc).w), p, false);  \
        p = dpp_xor1_add(p);                                                           \
        p = dpp_xor2_add(p);                                                           \
        p *= scale;                                                                    \
        p = ((bidx) < e1) ? p : -3.0e38f;                                              \
        float diff = p - m;                                                            \
        if (__any(diff > 8.f)) {                                                       \
            float mn = fmaxf(m, p);                                                    \
            float dd = exp2f(m - mn);                                                  \
            s *= dd;                                                                   \
            a0 *= dd; a1 *= dd; a2 *= dd; a3 *= dd;                                    \
            a4 *= dd; a5 *= dd; a6 *= dd; a7 *= dd;                                    \
            m = mn;                                                                    \
            diff = p - m;                                                              \
        }                                                                              \
        float wg = exp2f(diff);                                                        \
        s += wg;                                                                       \
        f16x2 vh0 = __builtin_bit_cast(f16x2, (vc).x);                                 \
        f16x2 vh1 = __builtin_bit_cast(f16x2, (vc).y);                                 \
        f16x2 vh2 = __builtin_bit_cast(f16x2, (vc).z);                                 \
        f16x2 vh3 = __builtin_bit_cast(f16x2, (vc).w);                                 \
        a0 += wg * (float)vh0[0]; a1 += wg * (float)vh0[1];                            \
        a2 += wg * (float)vh1[0]; a3 += wg * (float)vh1[1];                            \
        a4 += wg * (float)vh2[0]; a5 += wg * (float)vh2[1];                            \
        a6 += wg * (float)vh3[0]; a7 += wg * (float)vh3[1];                            \
    }

    int b = e0 + q4;
    for (int it = 0; it < niter2; it++) {
        {
            uint4 kc = k0, vc = v0;
            const uint32_t* r = kvw + (size_t)idx2 * 128;
            k0 = *reinterpret_cast<const uint4*>(r);
            v0 = *reinterpret_cast<const uint4*>(r + 64);
            idx2 = esrc[min(b + 12, last)];
            APROC(kc, vc, b);
            b += 4;
        }
        {
            uint4 kc = k1, vc = v1;
            const uint32_t* r = kvw + (size_t)idx2 * 128;
            k1 = *reinterpret_cast<const uint4*>(r);
            v1 = *reinterpret_cast<const uint4*>(r + 64);
            idx2 = esrc[min(b + 12, last)];
            APROC(kc, vc, b);
            b += 4;
        }
    }
#undef APROC

    // merge the 4 quarter-chains
#pragma unroll
    for (int off = 16; off <= 32; off <<= 1) {
        float m2 = __shfl_xor(m, off, 64);
        float s2 = __shfl_xor(s, off, 64);
        float b0 = __shfl_xor(a0, off, 64), b1 = __shfl_xor(a1, off, 64);
        float b2 = __shfl_xor(a2, off, 64), b3 = __shfl_xor(a3, off, 64);
        float b4 = __shfl_xor(a4, off, 64), b5 = __shfl_xor(a5, off, 64);
        float b6 = __shfl_xor(a6, off, 64), b7 = __shfl_xor(a7, off, 64);
        float mF = fmaxf(m, m2);
        float d1 = exp2f(m - mF), d2 = exp2f(m2 - mF);
        s = s * d1 + s2 * d2;
        a0 = a0 * d1 + b0 * d2; a1 = a1 * d1 + b1 * d2;
        a2 = a2 * d1 + b2 * d2; a3 = a3 * d1 + b3 * d2;
        a4 = a4 * d1 + b4 * d2; a5 = a5 * d1 + b5 * d2;
        a6 = a6 * d1 + b6 * d2; a7 = a7 * d1 + b7 * d2;
        m = mF;
    }

    float inv = 1.f / (s + 1e-9f);
    if (lane < 16) {
        uint4 o;
        o.x = pkh(a0 * inv, a1 * inv);
        o.y = pkh(a2 * inv, a3 * inv);
        o.z = pkh(a4 * inv, a5 * inv);
        o.w = pkh(a6 * inv, a7 * inv);
        *reinterpret_cast<uint4*>(outbase) = o;
    }
}

// ---------------------------------------------------------------------------
extern "C" void kernel_launch(void* const* d_in, const int* in_sizes, int n_in,
                              void* d_out, int out_size, void* d_ws, size_t ws_size,
                              hipStream_t stream) {
    const float* X    = (const float*)d_in[0];
    const float* Seed = (const float*)d_in[1];
    const float* Dg   = (const float*)d_in[2];
    const float* Cl   = (const float*)d_in[3];
    const int* esrc   = (const int*)d_in[4];
    const int* edst   = (const int*)d_in[5];
    const float* Wseed = (const float*)d_in[6];
    const float* Wdeg  = (const float*)d_in[7];
    const float* Wclu  = (const float*)d_in[8];
    const float* Wq = (const float*)d_in[9];
    const float* Wk = (const float*)d_in[10];
    const float* Wv = (const float*)d_in[11];
    const float* Wo = (const float*)d_in[12];
    const float* W1 = (const float*)d_in[13];
    const float* b1 = (const float*)d_in[14];
    const float* W2 = (const float*)d_in[15];
    const float* b2 = (const float*)d_in[16];
    float* out = (float*)d_out;

    int n = in_sizes[0];
    int E = in_sizes[4];

    char* p = (char*)d_ws;
    auto alloc = [&](size_t bytes) {
        void* r = (void*)p;
        p += (bytes + 255) & ~(size_t)255;
        return r;
    };
    _Float16* qbuf = (_Float16*)alloc((size_t)n * DM * 2);             // q fp16
    _Float16* abuf = (_Float16*)alloc((size_t)n * DM * 2);             // agg fp16
    unsigned short* kvbuf = (unsigned short*)alloc((size_t)n * 256 * 2);  // fp16 K|V
    _Float16* W16 = (_Float16*)alloc((size_t)13 * WSTRIDE * 2);        // packed weights
    int* deg    = (int*)alloc((size_t)n * 4);
    int* ptr    = (int*)alloc((size_t)(n + 1) * 4);
    int* ptrtmp = (int*)alloc((size_t)n * 4);
    int* bsums  = (int*)alloc(1024);
    int* fill   = (int*)alloc((size_t)n * 4);
    int* esrcs  = (int*)alloc((size_t)E * 4);
    (void)ws_size; (void)n_in; (void)out_size;

    hipMemsetAsync(deg, 0, (size_t)n * 4, stream);
    hipMemsetAsync(fill, 0, (size_t)n * 4, stream);

    int nb = (n + 255) / 256;
    count_kernel<<<(E + 255) / 256, 256, 0, stream>>>(edst, deg, E);
    scan1_kernel<<<nb, 256, 0, stream>>>(deg, ptrtmp, bsums, n);
    scan2_kernel<<<1, 256, 0, stream>>>(bsums, nb);
    scan3_kernel<<<nb, 256, 0, stream>>>(ptrtmp, bsums, ptr, n);
    scatter_kernel<<<(E + 255) / 256, 256, 0, stream>>>(esrc, edst, ptr, fill, esrcs, E);

    prepack_kernel<<<dim3(4, 8, 13), 64, 0, stream>>>(Wq, Wk, Wv, Wo, W1, W16);

    int ggrid = (n + 63) / 64;
    int agrid = (n + 3) / 4;
    const _Float16* KVc = (const _Float16*)kvbuf;

    // layer 1: embed fused into QKV
    fused_embed_qkv_kernel<<<ggrid, 256, 0, stream>>>(
        X, Seed, Dg, Cl, Wseed, Wdeg, Wclu,
        W16 + (size_t)0 * WSTRIDE, W16 + (size_t)3 * WSTRIDE, W16 + (size_t)6 * WSTRIDE,
        qbuf, (_Float16*)kvbuf, n);
    attn_kernel<<<agrid, 256, 0, stream>>>(qbuf, (const uint32_t*)KVc, ptr, esrcs, abuf, n);
    // layers 2,3: Wo fused into next QKV
    for (int i = 0; i < 2; i++) {
        fused_wo_qkv_kernel<<<ggrid, 256, 0, stream>>>(
            abuf, W16 + (size_t)(9 + i) * WSTRIDE,
            W16 + (size_t)(1 + i) * WSTRIDE, W16 + (size_t)(4 + i) * WSTRIDE,
            W16 + (size_t)(7 + i) * WSTRIDE, qbuf, (_Float16*)kvbuf, n);
        attn_kernel<<<agrid, 256, 0, stream>>>(qbuf, (const uint32_t*)KVc, ptr, esrcs, abuf, n);
    }
    // final: Wo3 fused with MLP head
    fused_wo_mlp_kernel<<<ggrid, 256, 0, stream>>>(
        abuf, W16 + (size_t)11 * WSTRIDE, W16 + (size_t)12 * WSTRIDE, b1, W2, b2, out, n);
}